// Round 1
// baseline (7934.216 us; speedup 1.0000x reference)
//
#include <hip/hip_runtime.h>

#define SP 1028  // padded LDS stride for S rows (1024 + 4)

// ---------------- conv3x3 on 32x32 images, IC=256, zero pad 1 ----------------
// grid: (N, OC/4), block 256. Each thread: 4 consecutive x pixels, 4 oc.
__global__ __launch_bounds__(256) void conv3x3_32(
    const float* __restrict__ in, const float* __restrict__ w,
    const float* __restrict__ bias, float* __restrict__ out,
    int out_nch, float scale)
{
    __shared__ float plane[34*34];
    const int n = blockIdx.x;
    const int ocg = blockIdx.y * 4;
    const int t = threadIdx.x;
    for (int i = t; i < 34*34; i += 256) plane[i] = 0.f;
    const int y = t >> 3;
    const int x0 = (t & 7) * 4;
    float acc[4][4];
    #pragma unroll
    for (int j = 0; j < 4; ++j)
        #pragma unroll
        for (int i = 0; i < 4; ++i) acc[j][i] = 0.f;
    const float* inb = in + (size_t)n * 256 * 1024;
    __syncthreads();
    for (int c = 0; c < 256; ++c) {
        float4 v = ((const float4*)(inb + c*1024))[t];
        int pbase = (y+1)*34 + x0 + 1;
        plane[pbase+0] = v.x; plane[pbase+1] = v.y;
        plane[pbase+2] = v.z; plane[pbase+3] = v.w;
        __syncthreads();
        float wr[4][9];
        #pragma unroll
        for (int j = 0; j < 4; ++j)
            #pragma unroll
            for (int k = 0; k < 9; ++k)
                wr[j][k] = w[((size_t)(ocg+j)*256 + c)*9 + k];
        float r[3][6];
        #pragma unroll
        for (int dy = 0; dy < 3; ++dy)
            #pragma unroll
            for (int dx = 0; dx < 6; ++dx)
                r[dy][dx] = plane[(y+dy)*34 + x0 + dx];
        #pragma unroll
        for (int j = 0; j < 4; ++j)
            #pragma unroll
            for (int i = 0; i < 4; ++i) {
                float s = acc[j][i];
                #pragma unroll
                for (int dy = 0; dy < 3; ++dy)
                    #pragma unroll
                    for (int dx = 0; dx < 3; ++dx)
                        s += r[dy][i+dx] * wr[j][dy*3+dx];
                acc[j][i] = s;
            }
        __syncthreads();
    }
    #pragma unroll
    for (int j = 0; j < 4; ++j) {
        int oc = ocg + j;
        float bb = bias[oc];
        #pragma unroll
        for (int i = 0; i < 4; ++i)
            out[((size_t)n*out_nch + oc)*1024 + y*32 + x0 + i] = (acc[j][i] + bb) * scale;
    }
}

// ---------------- bilinear (align-corners) resize f(H,W) -> fr(32,32) --------
__global__ __launch_bounds__(256) void resize32(
    const float* __restrict__ f, float* __restrict__ fr, int H, int W)
{
    int g = blockIdx.x * 256 + threadIdx.x;      // 2*256*1024 total
    int s = g & 1023;
    int c = (g >> 10) & 255;
    int b = g >> 18;
    int oy = s >> 5, ox = s & 31;
    float ty = (float)(oy * (H-1)) / 31.0f;
    float tx = (float)(ox * (W-1)) / 31.0f;
    int y0 = (int)ty; float wy = ty - y0;
    int y1 = min(y0+1, H-1);
    int x0 = (int)tx; float wx = tx - x0;
    int x1 = min(x0+1, W-1);
    const float* p = f + ((size_t)b*256 + c) * (size_t)(H*W);
    float v00 = p[y0*W+x0], v01 = p[y0*W+x1];
    float v10 = p[y1*W+x0], v11 = p[y1*W+x1];
    fr[g] = (v00*(1.f-wx) + v01*wx)*(1.f-wy) + (v10*(1.f-wx) + v11*wx)*wy;
}

// ---------------- fused attention: S = kq^T kt, softmax over m, PV with vt ---
// grid: (128 s-tiles of 8, 15 n, 2 b), block 256. atomicAdd into fin ch 128..255.
__global__ __launch_bounds__(256) void attn_kernel(
    const float* __restrict__ kq, const float* __restrict__ kt,
    const float* __restrict__ vt, float* __restrict__ fin)
{
    __shared__ __align__(16) float S[8*SP];
    __shared__ float ktt[32*8];
    __shared__ float red[32*8];
    __shared__ float colmax[8];
    __shared__ float colinv[8];
    const int t = threadIdx.x;
    const int s0 = blockIdx.x * 8;
    const int n = blockIdx.y;
    const int b = blockIdx.z;
    for (int i = t; i < 32*8; i += 256) {
        int c = i >> 3, ss = i & 7;
        ktt[i] = kt[((size_t)n*32 + c)*1024 + s0 + ss];
    }
    __syncthreads();
    // phase 1: thread owns m = 4t..4t+3 for all 8 s columns
    float4 accv[8];
    #pragma unroll
    for (int s = 0; s < 8; ++s) accv[s] = make_float4(0.f,0.f,0.f,0.f);
    const float* kqp = kq + (size_t)b*32*1024 + 4*t;
    #pragma unroll 4
    for (int c = 0; c < 32; ++c) {
        float4 q4 = *((const float4*)(kqp + c*1024));
        #pragma unroll
        for (int s = 0; s < 8; ++s) {
            float kv = ktt[c*8 + s];
            accv[s].x += q4.x*kv; accv[s].y += q4.y*kv;
            accv[s].z += q4.z*kv; accv[s].w += q4.w*kv;
        }
    }
    #pragma unroll
    for (int s = 0; s < 8; ++s)
        *((float4*)(S + s*SP + 4*t)) = accv[s];
    __syncthreads();
    // phase 2: column softmax over m (1024), strided-by-32 per-thread partition
    const int sI = t >> 5;
    const int part = t & 31;
    float mx = -1e30f;
    for (int mm = 0; mm < 32; ++mm)
        mx = fmaxf(mx, S[sI*SP + mm*32 + part]);
    red[part*8 + sI] = mx;
    __syncthreads();
    if (t < 8) {
        float m2 = -1e30f;
        for (int pp = 0; pp < 32; ++pp) m2 = fmaxf(m2, red[pp*8 + t]);
        colmax[t] = m2;
    }
    __syncthreads();
    float cm = colmax[sI];
    float ls = 0.f;
    for (int mm = 0; mm < 32; ++mm) {
        int idx = sI*SP + mm*32 + part;
        float e = __expf(S[idx] - cm);
        S[idx] = e;
        ls += e;
    }
    red[part*8 + sI] = ls;
    __syncthreads();
    if (t < 8) {
        float ssum = 0.f;
        for (int pp = 0; pp < 32; ++pp) ssum += red[pp*8 + t];
        colinv[t] = 1.f / ssum;
    }
    __syncthreads();
    // phase 3: PV. thread owns 2 c x 2 s, m in float4 steps.
    const int chalf = t & 63;
    const int spair = t >> 6;
    const int c0 = chalf * 2;
    const float* vt0 = vt + ((size_t)n*128 + c0)*1024;
    const float* vt1 = vt0 + 1024;
    const float* Sr0 = S + (spair*2+0)*SP;
    const float* Sr1 = S + (spair*2+1)*SP;
    float a00=0.f,a01=0.f,a10=0.f,a11=0.f;
    for (int m = 0; m < 1024; m += 4) {
        float4 v0 = *((const float4*)(vt0 + m));
        float4 v1 = *((const float4*)(vt1 + m));
        float4 p0 = *((const float4*)(Sr0 + m));
        float4 p1 = *((const float4*)(Sr1 + m));
        a00 += v0.x*p0.x + v0.y*p0.y + v0.z*p0.z + v0.w*p0.w;
        a01 += v0.x*p1.x + v0.y*p1.y + v0.z*p1.z + v0.w*p1.w;
        a10 += v1.x*p0.x + v1.y*p0.y + v1.z*p0.z + v1.w*p0.w;
        a11 += v1.x*p1.x + v1.y*p1.y + v1.z*p1.z + v1.w*p1.w;
    }
    float i0 = colinv[spair*2+0], i1 = colinv[spair*2+1];
    size_t base = ((size_t)b*256 + 128 + c0)*1024 + s0 + spair*2;
    atomicAdd(&fin[base + 0],        a00*i0);
    atomicAdd(&fin[base + 1],        a01*i1);
    atomicAdd(&fin[base + 1024 + 0], a10*i0);
    atomicAdd(&fin[base + 1024 + 1], a11*i1);
}

// ---------------- G = W2' * fin32 + bias'   (32x32 resolution conv1x1) ------
__global__ __launch_bounds__(256) void g_kernel(
    const float* __restrict__ fin, const float* __restrict__ W2t,
    const float* __restrict__ biasP, float* __restrict__ G)
{
    __shared__ float fv[256];
    int s = blockIdx.x & 1023;
    int b = blockIdx.x >> 10;
    int co = threadIdx.x;
    fv[co] = fin[((size_t)b*256 + co)*1024 + s];
    __syncthreads();
    float acc = biasP[co];
    #pragma unroll 8
    for (int ci = 0; ci < 256; ++ci)
        acc += W2t[ci*256 + co] * fv[ci];
    G[((size_t)b*256 + co)*1024 + s] = acc;
}

// ---------------- weight prep: transpose + fold BN into W2 / bias -----------
__global__ void prep_w(const float* __restrict__ cw, const float* __restrict__ gamma,
                       const float* __restrict__ var, float* __restrict__ W1t,
                       float* __restrict__ W2t)
{
    int ci = blockIdx.x, co = threadIdx.x;
    W1t[ci*256 + co] = cw[co*512 + ci];
    for (int l = 0; l < 5; ++l) {
        float g = gamma[l*256 + ci];
        float rs = rsqrtf(var[l*256 + ci] + 1e-5f);
        W2t[l*65536 + ci*256 + co] = cw[co*512 + 256 + ci] * g * rs;
    }
}

__global__ void prep_bias(const float* __restrict__ cw, const float* __restrict__ cb,
                          const float* __restrict__ gamma, const float* __restrict__ beta,
                          const float* __restrict__ mean, const float* __restrict__ var,
                          float* __restrict__ biasP)
{
    int l = blockIdx.x, co = threadIdx.x;
    float acc = cb[co];
    for (int ci = 0; ci < 256; ++ci) {
        float g = gamma[l*256+ci];
        float rs = rsqrtf(var[l*256+ci] + 1e-5f);
        float k = beta[l*256+ci] - g*rs*mean[l*256+ci];
        acc += cw[co*512 + 256 + ci] * k;
    }
    biasP[l*256 + co] = acc;
}

// ---------------- out = W1*f + bilerp(G)  (fused upsample+BN+conv1x1) -------
// grid: (ceil(HW/64), 2), block 256. Tile: 256 co x 64 px.
__global__ __launch_bounds__(256) void out_kernel(
    const float* __restrict__ f, const float* __restrict__ W1t,
    const float* __restrict__ G, float* __restrict__ outp,
    int H, int W)
{
    __shared__ __align__(16) float lds[16384];   // 64KB: fch (4KB) then transpose
    const int HW = H * W;
    const int p0 = blockIdx.x * 64;
    const int b = blockIdx.y;
    const int t = threadIdx.x;
    const int c4 = t & 63;
    const int pg = t >> 6;
    float acc[4][16];
    #pragma unroll
    for (int j = 0; j < 4; ++j)
        #pragma unroll
        for (int q = 0; q < 16; ++q) acc[j][q] = 0.f;
    for (int ci0 = 0; ci0 < 256; ci0 += 16) {
        __syncthreads();
        #pragma unroll
        for (int i = 0; i < 4; ++i) {
            int idx = t + 256*i;
            int cl = idx >> 6, pp = idx & 63;
            int p = p0 + pp;
            lds[cl*64 + pp] = (p < HW) ? f[((size_t)b*256 + ci0 + cl)*HW + p] : 0.f;
        }
        __syncthreads();
        #pragma unroll
        for (int cl = 0; cl < 16; ++cl) {
            float4 w4 = ((const float4*)(W1t + (ci0+cl)*256))[c4];
            const float4* fv = (const float4*)(lds + cl*64 + pg*16);
            float wv[4] = {w4.x, w4.y, w4.z, w4.w};
            #pragma unroll
            for (int q = 0; q < 4; ++q) {
                float4 fq = fv[q];
                #pragma unroll
                for (int j = 0; j < 4; ++j) {
                    acc[j][q*4+0] += wv[j]*fq.x;
                    acc[j][q*4+1] += wv[j]*fq.y;
                    acc[j][q*4+2] += wv[j]*fq.z;
                    acc[j][q*4+3] += wv[j]*fq.w;
                }
            }
        }
    }
    __syncthreads();
    // XOR-swizzled transpose to LDS so stores are coalesced
    #pragma unroll
    for (int j = 0; j < 4; ++j) {
        int co = c4*4 + j;
        #pragma unroll
        for (int q = 0; q < 4; ++q) {
            int chunk = pg*4 + q;
            float4 v = make_float4(acc[j][q*4+0], acc[j][q*4+1], acc[j][q*4+2], acc[j][q*4+3]);
            *((float4*)(lds + co*64 + ((chunk ^ (co & 15)) << 2))) = v;
        }
    }
    __syncthreads();
    const int lane = t & 63;
    const int wq = t >> 6;
    const int p = p0 + lane;
    const bool ok = p < HW;
    int yy = 0, xx = 0;
    if (ok) { yy = p / W; xx = p - yy*W; }
    float ty = (float)(yy*31) / (float)(H-1);
    float tx = (float)(xx*31) / (float)(W-1);
    int y0 = (int)ty; float wy = ty - y0;
    int x0 = (int)tx; float wx = tx - x0;
    int y1 = min(y0+1, 31);
    int x1 = min(x0+1, 31);
    float w00 = (1.f-wy)*(1.f-wx), w01 = (1.f-wy)*wx;
    float w10 = wy*(1.f-wx),       w11 = wy*wx;
    int i00 = y0*32+x0, i01 = y0*32+x1, i10 = y1*32+x0, i11 = y1*32+x1;
    for (int k = 0; k < 64; ++k) {
        int co = k*4 + wq;
        float tvv = lds[co*64 + (((lane>>2) ^ (co & 15)) << 2) + (lane & 3)];
        if (ok) {
            const float* gb = G + ((size_t)b*256 + co)*1024;
            float gv = gb[i00]*w00 + gb[i01]*w01 + gb[i10]*w10 + gb[i11]*w11;
            outp[((size_t)b*256 + co)*HW + p] = tvv + gv;
        }
    }
}

extern "C" void kernel_launch(void* const* d_in, const int* in_sizes, int n_in,
                              void* d_out, int out_size, void* d_ws, size_t ws_size,
                              hipStream_t stream)
{
    const float* f[5]; for (int i = 0; i < 5; ++i) f[i] = (const float*)d_in[i];
    const float* att   = (const float*)d_in[5];
    const float* ktw   = (const float*)d_in[6];
    const float* ktb   = (const float*)d_in[7];
    const float* vtw   = (const float*)d_in[8];
    const float* vtb   = (const float*)d_in[9];
    const float* kqw   = (const float*)d_in[10];
    const float* kqbb  = (const float*)d_in[11];
    const float* vqw   = (const float*)d_in[12];
    const float* vqb   = (const float*)d_in[13];
    const float* gamma = (const float*)d_in[14];
    const float* beta  = (const float*)d_in[15];
    const float* mean  = (const float*)d_in[16];
    const float* var   = (const float*)d_in[17];
    const float* cw    = (const float*)d_in[18];
    const float* cb    = (const float*)d_in[19];
    float* outp = (float*)d_out;

    float* ws    = (float*)d_ws;
    float* kt    = ws;                       // 15*32*1024
    float* vt    = kt  + 15*32*1024;         // 15*128*1024
    float* W1t   = vt  + 15*128*1024;        // 65536
    float* W2t   = W1t + 65536;              // 5*65536
    float* biasP = W2t + 5*65536;            // 5*256
    float* fr    = biasP + 5*256;            // 2*256*1024
    float* kqB   = fr  + 2*256*1024;         // 2*32*1024
    float* fin   = kqB + 2*32*1024;          // 2*256*1024
    float* G     = fin + 2*256*1024;         // 2*256*1024

    prep_w<<<256, 256, 0, stream>>>(cw, gamma, var, W1t, W2t);
    prep_bias<<<5, 256, 0, stream>>>(cw, cb, gamma, beta, mean, var, biasP);
    conv3x3_32<<<dim3(15, 8),  256, 0, stream>>>(att, ktw, ktb, kt, 32, 1.f);
    conv3x3_32<<<dim3(15, 32), 256, 0, stream>>>(att, vtw, vtb, vt, 128, 1.f);

    const int Hs[5] = {200,100,50,25,13};
    const int Ws[5] = {336,168,84,42,21};
    size_t ooff = 0;
    for (int l = 0; l < 5; ++l) {
        int H = Hs[l], W = Ws[l], HW = H*W;
        resize32<<<2048, 256, 0, stream>>>(f[l], fr, H, W);
        conv3x3_32<<<dim3(2, 8), 256, 0, stream>>>(fr, kqw + (size_t)l*32*256*9, kqbb + l*32, kqB, 32, 1.f);
        hipMemsetAsync(fin, 0, (size_t)2*256*1024*sizeof(float), stream);
        conv3x3_32<<<dim3(2, 32), 256, 0, stream>>>(fr, vqw + (size_t)l*128*256*9, vqb + l*128, fin, 256, 15.f);
        attn_kernel<<<dim3(128, 15, 2), 256, 0, stream>>>(kqB, kt, vt, fin);
        g_kernel<<<2048, 256, 0, stream>>>(fin, W2t + l*65536, biasP + l*256, G);
        out_kernel<<<dim3((HW+63)/64, 2), 256, 0, stream>>>(f[l], W1t, G, outp + ooff, H, W);
        ooff += (size_t)2*256*HW;
    }
}

// Round 2
// 3729.470 us; speedup vs baseline: 2.1274x; 2.1274x over previous
//
#include <hip/hip_runtime.h>

#define SP 1028  // padded LDS stride for S rows (1024 + 4)

// ---------------- weight transpose: w[oc][ic][3][3] -> wT[ic*9+k][oc] -------
__global__ __launch_bounds__(256) void transpose_w_k(
    const float* __restrict__ src, float* __restrict__ dst, int OC)
{
    int lev = blockIdx.y;
    const float* s = src + (size_t)lev * OC * 2304;
    float* d = dst + (size_t)lev * OC * 2304;
    int g = blockIdx.x * 256 + threadIdx.x;
    if (g < OC * 2304) {
        int oc = g / 2304;
        int rem = g - oc * 2304;           // ic*9 + k
        d[(size_t)rem * OC + oc] = s[g];
    }
}

// ---------------- init: out[n][c][s] = bias[c]*scale ------------------------
__global__ __launch_bounds__(256) void init_bias_k(
    float* __restrict__ out, const float* __restrict__ bias, float scale,
    int nch, int nstride, int total)
{
    int g = blockIdx.x * 256 + threadIdx.x;
    if (g >= total) return;
    int s = g & 1023;
    int rest = g >> 10;
    int c = rest % nch;
    int n = rest / nch;
    out[(size_t)n * nstride + c * 1024 + s] = bias[c] * scale;
}

// ---------------- conv3x3 on 32x32, IC-slice of 64, atomic accumulate -------
// grid: (4 rowgroups, OC/16, N*4 slices), block 256.
// Thread: 4 oc x 4 px. Weights pre-transposed wT[ic*9+k][OC].
__global__ __launch_bounds__(256) void conv3x3_v2(
    const float* __restrict__ in, const float* __restrict__ wT,
    float* __restrict__ out, int OC, int ostride, float scale)
{
    __shared__ float plane[4 * 340];       // 4 ch x 10 rows x 34 cols
    __shared__ float wlds[576];            // 4 ch x 9 k x 16 oc
    const int t = threadIdx.x;
    const int y0 = blockIdx.x * 8;
    const int oc0 = blockIdx.y * 16;
    const int n = blockIdx.z >> 2;
    const int ic0 = (blockIdx.z & 3) * 64;

    const int ocg = t & 3;
    const int pxg = t >> 2;
    const int yl = pxg >> 3;
    const int x0l = (pxg & 7) * 4;

    float acc[4][4];
    #pragma unroll
    for (int j = 0; j < 4; ++j)
        #pragma unroll
        for (int i = 0; i < 4; ++i) acc[j][i] = 0.f;

    const size_t inbase = (size_t)n * 262144;   // 256*1024

    for (int cs = 0; cs < 16; ++cs) {
        __syncthreads();
        // stage 4 input planes (10x34 padded window)
        #pragma unroll
        for (int i = 0; i < 6; ++i) {
            int lin = t + 256 * i;
            if (lin < 1360) {
                int ch = lin / 340, rem = lin - 340 * ch;
                int row = rem / 34, col = rem - 34 * row;
                int gy = y0 - 1 + row, gx = col - 1;
                float v = 0.f;
                if (gy >= 0 && gy < 32 && gx >= 0 && gx < 32)
                    v = in[inbase + (size_t)(ic0 + cs * 4 + ch) * 1024 + gy * 32 + gx];
                plane[ch * 340 + rem] = v;
            }
        }
        // stage weights: 4 ch x 9 k x 16 oc
        const size_t wTbase = (size_t)(ic0 + cs * 4) * 9 * OC + oc0;
        #pragma unroll
        for (int i = 0; i < 3; ++i) {
            int lin = t + 256 * i;
            if (lin < 576) {
                int oc = lin & 15, kk = lin >> 4;
                wlds[lin] = wT[wTbase + (size_t)kk * OC + oc];
            }
        }
        __syncthreads();
        #pragma unroll
        for (int ch = 0; ch < 4; ++ch) {
            float4 wr[9];
            #pragma unroll
            for (int k = 0; k < 9; ++k)
                wr[k] = *((const float4*)&wlds[(ch * 9 + k) * 16 + ocg * 4]);
            float r[3][6];
            #pragma unroll
            for (int dy = 0; dy < 3; ++dy)
                #pragma unroll
                for (int dx = 0; dx < 6; ++dx)
                    r[dy][dx] = plane[ch * 340 + (yl + dy) * 34 + x0l + dx];
            #pragma unroll
            for (int j = 0; j < 4; ++j)
                #pragma unroll
                for (int i = 0; i < 4; ++i) {
                    float s = acc[j][i];
                    #pragma unroll
                    for (int dy = 0; dy < 3; ++dy)
                        #pragma unroll
                        for (int dx = 0; dx < 3; ++dx) {
                            float wv;
                            const float4 w4 = wr[dy * 3 + dx];
                            wv = (j == 0) ? w4.x : (j == 1) ? w4.y : (j == 2) ? w4.z : w4.w;
                            s += r[dy][i + dx] * wv;
                        }
                    acc[j][i] = s;
                }
        }
    }
    #pragma unroll
    for (int j = 0; j < 4; ++j) {
        int oc = oc0 + ocg * 4 + j;
        #pragma unroll
        for (int i = 0; i < 4; ++i)
            atomicAdd(&out[(size_t)n * ostride + (size_t)oc * 1024 + (y0 + yl) * 32 + x0l + i],
                      acc[j][i] * scale);
    }
}

// ---------------- vt[15][128][1024] -> vtT[15][1024][128] -------------------
__global__ __launch_bounds__(256) void transpose_vt(
    const float* __restrict__ vt, float* __restrict__ vtT)
{
    __shared__ float tile[32][33];
    const int n = blockIdx.z;
    const int cb = blockIdx.y * 32;
    const int mb = blockIdx.x * 32;
    const int tx = threadIdx.x & 31;
    const int ty = threadIdx.x >> 5;
    for (int i = ty; i < 32; i += 8)
        tile[i][tx] = vt[((size_t)n * 128 + cb + i) * 1024 + mb + tx];
    __syncthreads();
    for (int i = ty; i < 32; i += 8)
        vtT[((size_t)n * 1024 + mb + i) * 128 + cb + tx] = tile[tx][i];
}

// ---------------- bilinear (align-corners) resize f(H,W) -> fr(32,32) --------
__global__ __launch_bounds__(256) void resize32(
    const float* __restrict__ f, float* __restrict__ fr, int H, int W)
{
    int g = blockIdx.x * 256 + threadIdx.x;      // 2*256*1024 total
    int s = g & 1023;
    int c = (g >> 10) & 255;
    int b = g >> 18;
    int oy = s >> 5, ox = s & 31;
    float ty = (float)(oy * (H-1)) / 31.0f;
    float tx = (float)(ox * (W-1)) / 31.0f;
    int y0 = (int)ty; float wy = ty - y0;
    int y1 = min(y0+1, H-1);
    int x0 = (int)tx; float wx = tx - x0;
    int x1 = min(x0+1, W-1);
    const float* p = f + ((size_t)b*256 + c) * (size_t)(H*W);
    float v00 = p[y0*W+x0], v01 = p[y0*W+x1];
    float v10 = p[y1*W+x0], v11 = p[y1*W+x1];
    fr[g] = (v00*(1.f-wx) + v01*wx)*(1.f-wy) + (v10*(1.f-wx) + v11*wx)*wy;
}

// ---------------- fused attention: S = kq^T kt, softmax over m, PV ----------
// grid: (128 s-tiles of 8, 15 n, 2 b), block 256. Coalesced PV via vtT.
__global__ __launch_bounds__(256) void attn_kernel(
    const float* __restrict__ kq, const float* __restrict__ kt,
    const float* __restrict__ vtT, float* __restrict__ fin)
{
    __shared__ __align__(16) float S[8*SP];
    __shared__ float ktt[32*8];
    __shared__ float red[32*8];
    __shared__ float colmax[8];
    __shared__ float colinv[8];
    __shared__ float Cbuf[128*8];
    const int t = threadIdx.x;
    const int s0 = blockIdx.x * 8;
    const int n = blockIdx.y;
    const int b = blockIdx.z;
    for (int i = t; i < 32*8; i += 256) {
        int c = i >> 3, ss = i & 7;
        ktt[i] = kt[((size_t)n*32 + c)*1024 + s0 + ss];
    }
    __syncthreads();
    // phase 1: thread owns m = 4t..4t+3 for all 8 s columns
    float4 accv[8];
    #pragma unroll
    for (int s = 0; s < 8; ++s) accv[s] = make_float4(0.f,0.f,0.f,0.f);
    const float* kqp = kq + (size_t)b*32*1024 + 4*t;
    #pragma unroll 4
    for (int c = 0; c < 32; ++c) {
        float4 q4 = *((const float4*)(kqp + c*1024));
        #pragma unroll
        for (int s = 0; s < 8; ++s) {
            float kv = ktt[c*8 + s];
            accv[s].x += q4.x*kv; accv[s].y += q4.y*kv;
            accv[s].z += q4.z*kv; accv[s].w += q4.w*kv;
        }
    }
    #pragma unroll
    for (int s = 0; s < 8; ++s)
        *((float4*)(S + s*SP + 4*t)) = accv[s];
    __syncthreads();
    // phase 2: column softmax over m (1024)
    const int sI = t >> 5;
    const int part = t & 31;
    float mx = -1e30f;
    for (int mm = 0; mm < 32; ++mm)
        mx = fmaxf(mx, S[sI*SP + mm*32 + part]);
    red[part*8 + sI] = mx;
    __syncthreads();
    if (t < 8) {
        float m2 = -1e30f;
        for (int pp = 0; pp < 32; ++pp) m2 = fmaxf(m2, red[pp*8 + t]);
        colmax[t] = m2;
    }
    __syncthreads();
    float cm = colmax[sI];
    float ls = 0.f;
    for (int mm = 0; mm < 32; ++mm) {
        int idx = sI*SP + mm*32 + part;
        float e = __expf(S[idx] - cm);
        S[idx] = e;
        ls += e;
    }
    red[part*8 + sI] = ls;
    __syncthreads();
    if (t < 8) {
        float ssum = 0.f;
        for (int pp = 0; pp < 32; ++pp) ssum += red[pp*8 + t];
        colinv[t] = 1.f / ssum;
    }
    __syncthreads();
    // phase 3: PV, coalesced over channels via vtT. c = t&127, m-half = t>>7.
    const int c = t & 127;
    const int mh = t >> 7;
    float acc[8];
    #pragma unroll
    for (int s = 0; s < 8; ++s) acc[s] = 0.f;
    const float* vcol = vtT + ((size_t)n*1024 + (size_t)mh*512)*128 + c;
    const float* Sb = S + mh*512;
    #pragma unroll 4
    for (int mm = 0; mm < 512; mm += 4) {
        float v0 = vcol[(mm+0)*128];
        float v1 = vcol[(mm+1)*128];
        float v2 = vcol[(mm+2)*128];
        float v3 = vcol[(mm+3)*128];
        #pragma unroll
        for (int s = 0; s < 8; ++s) {
            float4 p = *((const float4*)(Sb + s*SP + mm));
            acc[s] += v0*p.x + v1*p.y + v2*p.z + v3*p.w;
        }
    }
    if (t >= 128) {
        #pragma unroll
        for (int s = 0; s < 8; ++s) Cbuf[(t-128)*8 + s] = acc[s];
    }
    __syncthreads();
    if (t < 128) {
        size_t base = ((size_t)b*256 + 128 + c)*1024 + s0;
        #pragma unroll
        for (int s = 0; s < 8; ++s)
            atomicAdd(&fin[base + s], (acc[s] + Cbuf[c*8 + s]) * colinv[s]);
    }
}

// ---------------- G = W2' * fin32 + bias'   (32x32 resolution conv1x1) ------
__global__ __launch_bounds__(256) void g_kernel(
    const float* __restrict__ fin, const float* __restrict__ W2t,
    const float* __restrict__ biasP, float* __restrict__ G)
{
    __shared__ float fv[256];
    int s = blockIdx.x & 1023;
    int b = blockIdx.x >> 10;
    int co = threadIdx.x;
    fv[co] = fin[((size_t)b*256 + co)*1024 + s];
    __syncthreads();
    float acc = biasP[co];
    #pragma unroll 8
    for (int ci = 0; ci < 256; ++ci)
        acc += W2t[ci*256 + co] * fv[ci];
    G[((size_t)b*256 + co)*1024 + s] = acc;
}

// ---------------- weight prep: transpose + fold BN into W2 / bias -----------
__global__ void prep_w(const float* __restrict__ cw, const float* __restrict__ gamma,
                       const float* __restrict__ var, float* __restrict__ W1t,
                       float* __restrict__ W2t)
{
    int ci = blockIdx.x, co = threadIdx.x;
    W1t[ci*256 + co] = cw[co*512 + ci];
    for (int l = 0; l < 5; ++l) {
        float g = gamma[l*256 + ci];
        float rs = rsqrtf(var[l*256 + ci] + 1e-5f);
        W2t[l*65536 + ci*256 + co] = cw[co*512 + 256 + ci] * g * rs;
    }
}

__global__ void prep_bias(const float* __restrict__ cw, const float* __restrict__ cb,
                          const float* __restrict__ gamma, const float* __restrict__ beta,
                          const float* __restrict__ mean, const float* __restrict__ var,
                          float* __restrict__ biasP)
{
    int l = blockIdx.x, co = threadIdx.x;
    float acc = cb[co];
    for (int ci = 0; ci < 256; ++ci) {
        float g = gamma[l*256+ci];
        float rs = rsqrtf(var[l*256+ci] + 1e-5f);
        float k = beta[l*256+ci] - g*rs*mean[l*256+ci];
        acc += cw[co*512 + 256 + ci] * k;
    }
    biasP[l*256 + co] = acc;
}

// ---------------- out = W1*f + bilerp(G)  (fused upsample+BN+conv1x1) -------
__global__ __launch_bounds__(256) void out_kernel(
    const float* __restrict__ f, const float* __restrict__ W1t,
    const float* __restrict__ G, float* __restrict__ outp,
    int H, int W)
{
    __shared__ __align__(16) float lds[16384];
    const int HW = H * W;
    const int p0 = blockIdx.x * 64;
    const int b = blockIdx.y;
    const int t = threadIdx.x;
    const int c4 = t & 63;
    const int pg = t >> 6;
    float acc[4][16];
    #pragma unroll
    for (int j = 0; j < 4; ++j)
        #pragma unroll
        for (int q = 0; q < 16; ++q) acc[j][q] = 0.f;
    for (int ci0 = 0; ci0 < 256; ci0 += 16) {
        __syncthreads();
        #pragma unroll
        for (int i = 0; i < 4; ++i) {
            int idx = t + 256*i;
            int cl = idx >> 6, pp = idx & 63;
            int p = p0 + pp;
            lds[cl*64 + pp] = (p < HW) ? f[((size_t)b*256 + ci0 + cl)*HW + p] : 0.f;
        }
        __syncthreads();
        #pragma unroll
        for (int cl = 0; cl < 16; ++cl) {
            float4 w4 = ((const float4*)(W1t + (ci0+cl)*256))[c4];
            const float4* fv = (const float4*)(lds + cl*64 + pg*16);
            float wv[4] = {w4.x, w4.y, w4.z, w4.w};
            #pragma unroll
            for (int q = 0; q < 4; ++q) {
                float4 fq = fv[q];
                #pragma unroll
                for (int j = 0; j < 4; ++j) {
                    acc[j][q*4+0] += wv[j]*fq.x;
                    acc[j][q*4+1] += wv[j]*fq.y;
                    acc[j][q*4+2] += wv[j]*fq.z;
                    acc[j][q*4+3] += wv[j]*fq.w;
                }
            }
        }
    }
    __syncthreads();
    #pragma unroll
    for (int j = 0; j < 4; ++j) {
        int co = c4*4 + j;
        #pragma unroll
        for (int q = 0; q < 4; ++q) {
            int chunk = pg*4 + q;
            float4 v = make_float4(acc[j][q*4+0], acc[j][q*4+1], acc[j][q*4+2], acc[j][q*4+3]);
            *((float4*)(lds + co*64 + ((chunk ^ (co & 15)) << 2))) = v;
        }
    }
    __syncthreads();
    const int lane = t & 63;
    const int wq = t >> 6;
    const int p = p0 + lane;
    const bool ok = p < HW;
    int yy = 0, xx = 0;
    if (ok) { yy = p / W; xx = p - yy*W; }
    float ty = (float)(yy*31) / (float)(H-1);
    float tx = (float)(xx*31) / (float)(W-1);
    int y0 = (int)ty; float wy = ty - y0;
    int x0 = (int)tx; float wx = tx - x0;
    int y1 = min(y0+1, 31);
    int x1 = min(x0+1, 31);
    float w00 = (1.f-wy)*(1.f-wx), w01 = (1.f-wy)*wx;
    float w10 = wy*(1.f-wx),       w11 = wy*wx;
    int i00 = y0*32+x0, i01 = y0*32+x1, i10 = y1*32+x0, i11 = y1*32+x1;
    for (int k = 0; k < 64; ++k) {
        int co = k*4 + wq;
        float tvv = lds[co*64 + (((lane>>2) ^ (co & 15)) << 2) + (lane & 3)];
        if (ok) {
            const float* gb = G + ((size_t)b*256 + co)*1024;
            float gv = gb[i00]*w00 + gb[i01]*w01 + gb[i10]*w10 + gb[i11]*w11;
            outp[((size_t)b*256 + co)*HW + p] = tvv + gv;
        }
    }
}

extern "C" void kernel_launch(void* const* d_in, const int* in_sizes, int n_in,
                              void* d_out, int out_size, void* d_ws, size_t ws_size,
                              hipStream_t stream)
{
    const float* f[5]; for (int i = 0; i < 5; ++i) f[i] = (const float*)d_in[i];
    const float* att   = (const float*)d_in[5];
    const float* ktw   = (const float*)d_in[6];
    const float* ktb   = (const float*)d_in[7];
    const float* vtw   = (const float*)d_in[8];
    const float* vtb   = (const float*)d_in[9];
    const float* kqw   = (const float*)d_in[10];
    const float* kqbb  = (const float*)d_in[11];
    const float* vqw   = (const float*)d_in[12];
    const float* vqb   = (const float*)d_in[13];
    const float* gamma = (const float*)d_in[14];
    const float* beta  = (const float*)d_in[15];
    const float* mean  = (const float*)d_in[16];
    const float* var   = (const float*)d_in[17];
    const float* cw    = (const float*)d_in[18];
    const float* cb    = (const float*)d_in[19];
    float* outp = (float*)d_out;

    float* ws    = (float*)d_ws;
    float* kt    = ws;                        // 15*32*1024   = 491520
    float* vt    = kt   + 491520;             // 15*128*1024  = 1966080
    float* vtT   = vt   + 1966080;            // 1966080
    float* W1t   = vtT  + 1966080;            // 65536
    float* W2t   = W1t  + 65536;              // 327680
    float* biasP = W2t  + 327680;             // 1280
    float* fr    = biasP + 1280;              // 524288
    float* kqB   = fr   + 524288;             // 65536
    float* fin   = kqB  + 65536;              // 524288
    float* G     = fin  + 524288;             // 524288
    float* wTkt  = G    + 524288;             // 73728
    float* wTvt  = wTkt + 73728;              // 294912
    float* wTkq  = wTvt + 294912;             // 368640
    float* wTvq  = wTkq + 368640;             // 1474560

    prep_w<<<256, 256, 0, stream>>>(cw, gamma, var, W1t, W2t);
    prep_bias<<<5, 256, 0, stream>>>(cw, cb, gamma, beta, mean, var, biasP);
    transpose_w_k<<<dim3(288, 1),  256, 0, stream>>>(ktw, wTkt, 32);
    transpose_w_k<<<dim3(1152, 1), 256, 0, stream>>>(vtw, wTvt, 128);
    transpose_w_k<<<dim3(288, 5),  256, 0, stream>>>(kqw, wTkq, 32);
    transpose_w_k<<<dim3(1152, 5), 256, 0, stream>>>(vqw, wTvq, 128);

    init_bias_k<<<1920, 256, 0, stream>>>(kt, ktb, 1.f, 32, 32768, 491520);
    init_bias_k<<<7680, 256, 0, stream>>>(vt, vtb, 1.f, 128, 131072, 1966080);
    conv3x3_v2<<<dim3(4, 2, 60), 256, 0, stream>>>(att, wTkt, kt, 32, 32768, 1.f);
    conv3x3_v2<<<dim3(4, 8, 60), 256, 0, stream>>>(att, wTvt, vt, 128, 131072, 1.f);
    transpose_vt<<<dim3(32, 4, 15), 256, 0, stream>>>(vt, vtT);

    const int Hs[5] = {200,100,50,25,13};
    const int Ws[5] = {336,168,84,42,21};
    size_t ooff = 0;
    for (int l = 0; l < 5; ++l) {
        int H = Hs[l], W = Ws[l], HW = H*W;
        resize32<<<2048, 256, 0, stream>>>(f[l], fr, H, W);
        init_bias_k<<<256, 256, 0, stream>>>(kqB, kqbb + l*32, 1.f, 32, 32768, 65536);
        conv3x3_v2<<<dim3(4, 2, 8), 256, 0, stream>>>(fr, wTkq + (size_t)l*73728, kqB, 32, 32768, 1.f);
        hipMemsetAsync(fin, 0, (size_t)2*256*1024*sizeof(float), stream);
        init_bias_k<<<1024, 256, 0, stream>>>(fin, vqb + l*128, 15.f, 128, 262144, 262144);
        conv3x3_v2<<<dim3(4, 8, 8), 256, 0, stream>>>(fr, wTvq + (size_t)l*294912, fin, 128, 262144, 15.f);
        attn_kernel<<<dim3(128, 15, 2), 256, 0, stream>>>(kqB, kt, vtT, fin);
        g_kernel<<<2048, 256, 0, stream>>>(fin, W2t + l*65536, biasP + l*256, G);
        out_kernel<<<dim3((HW+63)/64, 2), 256, 0, stream>>>(f[l], W1t, G, outp + ooff, H, W);
        ooff += (size_t)2*256*HW;
    }
}

// Round 3
// 3137.354 us; speedup vs baseline: 2.5290x; 1.1887x over previous
//
#include <hip/hip_runtime.h>

#define SP 1028  // padded LDS stride for S rows (1024 + 4)

typedef __attribute__((ext_vector_type(8))) short bfrag;
typedef __attribute__((ext_vector_type(4))) float f4acc;

__device__ inline unsigned short f2bf(float x) {
    unsigned u = __float_as_uint(x);
    unsigned r = (u + 0x7FFF + ((u >> 16) & 1)) >> 16;
    return (unsigned short)r;
}

// ---------------- weight transpose: w[oc][ic][3][3] -> wT[ic*9+k][oc] -------
__global__ __launch_bounds__(256) void transpose_w_k(
    const float* __restrict__ src, float* __restrict__ dst, int OC)
{
    int lev = blockIdx.y;
    const float* s = src + (size_t)lev * OC * 2304;
    float* d = dst + (size_t)lev * OC * 2304;
    int g = blockIdx.x * 256 + threadIdx.x;
    if (g < OC * 2304) {
        int oc = g / 2304;
        int rem = g - oc * 2304;           // ic*9 + k
        d[(size_t)rem * OC + oc] = s[g];
    }
}

// ---------------- init: out[n][c][s] = bias[c]*scale ------------------------
__global__ __launch_bounds__(256) void init_bias_k(
    float* __restrict__ out, const float* __restrict__ bias, float scale,
    int nch, int nstride, int total)
{
    int g = blockIdx.x * 256 + threadIdx.x;
    if (g >= total) return;
    int s = g & 1023;
    int rest = g >> 10;
    int c = rest % nch;
    int n = rest / nch;
    out[(size_t)n * nstride + c * 1024 + s] = bias[c] * scale;
}

// ---------------- conv3x3 on 32x32, IC-slice of 64, atomic accumulate -------
__global__ __launch_bounds__(256) void conv3x3_v2(
    const float* __restrict__ in, const float* __restrict__ wT,
    float* __restrict__ out, int OC, int ostride, float scale)
{
    __shared__ float plane[4 * 340];       // 4 ch x 10 rows x 34 cols
    __shared__ float wlds[576];            // 4 ch x 9 k x 16 oc
    const int t = threadIdx.x;
    const int y0 = blockIdx.x * 8;
    const int oc0 = blockIdx.y * 16;
    const int n = blockIdx.z >> 2;
    const int ic0 = (blockIdx.z & 3) * 64;

    const int ocg = t & 3;
    const int pxg = t >> 2;
    const int yl = pxg >> 3;
    const int x0l = (pxg & 7) * 4;

    float acc[4][4];
    #pragma unroll
    for (int j = 0; j < 4; ++j)
        #pragma unroll
        for (int i = 0; i < 4; ++i) acc[j][i] = 0.f;

    const size_t inbase = (size_t)n * 262144;

    for (int cs = 0; cs < 16; ++cs) {
        __syncthreads();
        #pragma unroll
        for (int i = 0; i < 6; ++i) {
            int lin = t + 256 * i;
            if (lin < 1360) {
                int ch = lin / 340, rem = lin - 340 * ch;
                int row = rem / 34, col = rem - 34 * row;
                int gy = y0 - 1 + row, gx = col - 1;
                float v = 0.f;
                if (gy >= 0 && gy < 32 && gx >= 0 && gx < 32)
                    v = in[inbase + (size_t)(ic0 + cs * 4 + ch) * 1024 + gy * 32 + gx];
                plane[ch * 340 + rem] = v;
            }
        }
        const size_t wTbase = (size_t)(ic0 + cs * 4) * 9 * OC + oc0;
        #pragma unroll
        for (int i = 0; i < 3; ++i) {
            int lin = t + 256 * i;
            if (lin < 576) {
                int oc = lin & 15, kk = lin >> 4;
                wlds[lin] = wT[wTbase + (size_t)kk * OC + oc];
            }
        }
        __syncthreads();
        #pragma unroll
        for (int ch = 0; ch < 4; ++ch) {
            float4 wr[9];
            #pragma unroll
            for (int k = 0; k < 9; ++k)
                wr[k] = *((const float4*)&wlds[(ch * 9 + k) * 16 + ocg * 4]);
            float r[3][6];
            #pragma unroll
            for (int dy = 0; dy < 3; ++dy)
                #pragma unroll
                for (int dx = 0; dx < 6; ++dx)
                    r[dy][dx] = plane[ch * 340 + (yl + dy) * 34 + x0l + dx];
            #pragma unroll
            for (int j = 0; j < 4; ++j)
                #pragma unroll
                for (int i = 0; i < 4; ++i) {
                    float s = acc[j][i];
                    #pragma unroll
                    for (int dy = 0; dy < 3; ++dy)
                        #pragma unroll
                        for (int dx = 0; dx < 3; ++dx) {
                            float wv;
                            const float4 w4 = wr[dy * 3 + dx];
                            wv = (j == 0) ? w4.x : (j == 1) ? w4.y : (j == 2) ? w4.z : w4.w;
                            s += r[dy][i + dx] * wv;
                        }
                    acc[j][i] = s;
                }
        }
    }
    #pragma unroll
    for (int j = 0; j < 4; ++j) {
        int oc = oc0 + ocg * 4 + j;
        #pragma unroll
        for (int i = 0; i < 4; ++i)
            atomicAdd(&out[(size_t)n * ostride + (size_t)oc * 1024 + (y0 + yl) * 32 + x0l + i],
                      acc[j][i] * scale);
    }
}

// ---------------- vt[15][128][1024] -> vtT[15][1024][128] -------------------
__global__ __launch_bounds__(256) void transpose_vt(
    const float* __restrict__ vt, float* __restrict__ vtT)
{
    __shared__ float tile[32][33];
    const int n = blockIdx.z;
    const int cb = blockIdx.y * 32;
    const int mb = blockIdx.x * 32;
    const int tx = threadIdx.x & 31;
    const int ty = threadIdx.x >> 5;
    for (int i = ty; i < 32; i += 8)
        tile[i][tx] = vt[((size_t)n * 128 + cb + i) * 1024 + mb + tx];
    __syncthreads();
    for (int i = ty; i < 32; i += 8)
        vtT[((size_t)n * 1024 + mb + i) * 128 + cb + tx] = tile[tx][i];
}

// ---------------- bilinear (align-corners) resize f(H,W) -> fr(32,32) --------
__global__ __launch_bounds__(256) void resize32(
    const float* __restrict__ f, float* __restrict__ fr, int H, int W)
{
    int g = blockIdx.x * 256 + threadIdx.x;
    int s = g & 1023;
    int c = (g >> 10) & 255;
    int b = g >> 18;
    int oy = s >> 5, ox = s & 31;
    float ty = (float)(oy * (H-1)) / 31.0f;
    float tx = (float)(ox * (W-1)) / 31.0f;
    int y0 = (int)ty; float wy = ty - y0;
    int y1 = min(y0+1, H-1);
    int x0 = (int)tx; float wx = tx - x0;
    int x1 = min(x0+1, W-1);
    const float* p = f + ((size_t)b*256 + c) * (size_t)(H*W);
    float v00 = p[y0*W+x0], v01 = p[y0*W+x1];
    float v10 = p[y1*W+x0], v11 = p[y1*W+x1];
    fr[g] = (v00*(1.f-wx) + v01*wx)*(1.f-wy) + (v10*(1.f-wx) + v11*wx)*wy;
}

// ---------------- fused attention: S = kq^T kt, softmax over m, PV ----------
__global__ __launch_bounds__(256) void attn_kernel(
    const float* __restrict__ kq, const float* __restrict__ kt,
    const float* __restrict__ vtT, float* __restrict__ fin)
{
    __shared__ __align__(16) float S[8*SP];
    __shared__ float ktt[32*8];
    __shared__ float red[32*8];
    __shared__ float colmax[8];
    __shared__ float colinv[8];
    __shared__ float Cbuf[128*8];
    const int t = threadIdx.x;
    const int s0 = blockIdx.x * 8;
    const int n = blockIdx.y;
    const int b = blockIdx.z;
    for (int i = t; i < 32*8; i += 256) {
        int c = i >> 3, ss = i & 7;
        ktt[i] = kt[((size_t)n*32 + c)*1024 + s0 + ss];
    }
    __syncthreads();
    float4 accv[8];
    #pragma unroll
    for (int s = 0; s < 8; ++s) accv[s] = make_float4(0.f,0.f,0.f,0.f);
    const float* kqp = kq + (size_t)b*32*1024 + 4*t;
    #pragma unroll 4
    for (int c = 0; c < 32; ++c) {
        float4 q4 = *((const float4*)(kqp + c*1024));
        #pragma unroll
        for (int s = 0; s < 8; ++s) {
            float kv = ktt[c*8 + s];
            accv[s].x += q4.x*kv; accv[s].y += q4.y*kv;
            accv[s].z += q4.z*kv; accv[s].w += q4.w*kv;
        }
    }
    #pragma unroll
    for (int s = 0; s < 8; ++s)
        *((float4*)(S + s*SP + 4*t)) = accv[s];
    __syncthreads();
    const int sI = t >> 5;
    const int part = t & 31;
    float mx = -1e30f;
    for (int mm = 0; mm < 32; ++mm)
        mx = fmaxf(mx, S[sI*SP + mm*32 + part]);
    red[part*8 + sI] = mx;
    __syncthreads();
    if (t < 8) {
        float m2 = -1e30f;
        for (int pp = 0; pp < 32; ++pp) m2 = fmaxf(m2, red[pp*8 + t]);
        colmax[t] = m2;
    }
    __syncthreads();
    float cm = colmax[sI];
    float ls = 0.f;
    for (int mm = 0; mm < 32; ++mm) {
        int idx = sI*SP + mm*32 + part;
        float e = __expf(S[idx] - cm);
        S[idx] = e;
        ls += e;
    }
    red[part*8 + sI] = ls;
    __syncthreads();
    if (t < 8) {
        float ssum = 0.f;
        for (int pp = 0; pp < 32; ++pp) ssum += red[pp*8 + t];
        colinv[t] = 1.f / ssum;
    }
    __syncthreads();
    const int c = t & 127;
    const int mh = t >> 7;
    float acc[8];
    #pragma unroll
    for (int s = 0; s < 8; ++s) acc[s] = 0.f;
    const float* vcol = vtT + ((size_t)n*1024 + (size_t)mh*512)*128 + c;
    const float* Sb = S + mh*512;
    #pragma unroll 4
    for (int mm = 0; mm < 512; mm += 4) {
        float v0 = vcol[(mm+0)*128];
        float v1 = vcol[(mm+1)*128];
        float v2 = vcol[(mm+2)*128];
        float v3 = vcol[(mm+3)*128];
        #pragma unroll
        for (int s = 0; s < 8; ++s) {
            float4 p = *((const float4*)(Sb + s*SP + mm));
            acc[s] += v0*p.x + v1*p.y + v2*p.z + v3*p.w;
        }
    }
    if (t >= 128) {
        #pragma unroll
        for (int s = 0; s < 8; ++s) Cbuf[(t-128)*8 + s] = acc[s];
    }
    __syncthreads();
    if (t < 128) {
        size_t base = ((size_t)b*256 + 128 + c)*1024 + s0;
        #pragma unroll
        for (int s = 0; s < 8; ++s)
            atomicAdd(&fin[base + s], (acc[s] + Cbuf[c*8 + s]) * colinv[s]);
    }
}

// ---------------- G = W2' * fin32 + bias'   (32x32 resolution conv1x1) ------
__global__ __launch_bounds__(256) void g_kernel(
    const float* __restrict__ fin, const float* __restrict__ W2t,
    const float* __restrict__ biasP, float* __restrict__ G)
{
    __shared__ float fv[256];
    int s = blockIdx.x & 1023;
    int b = blockIdx.x >> 10;
    int co = threadIdx.x;
    fv[co] = fin[((size_t)b*256 + co)*1024 + s];
    __syncthreads();
    float acc = biasP[co];
    #pragma unroll 8
    for (int ci = 0; ci < 256; ++ci)
        acc += W2t[ci*256 + co] * fv[ci];
    G[((size_t)b*256 + co)*1024 + s] = acc;
}

// -------- weight prep: W1 -> bf16 packed [kstep][co][32]; fold BN into W2 ---
__global__ void prep_w(const float* __restrict__ cw, const float* __restrict__ gamma,
                       const float* __restrict__ var, unsigned short* __restrict__ W1s,
                       float* __restrict__ W2t)
{
    int ci = blockIdx.x, co = threadIdx.x;
    W1s[(ci >> 5) * 8192 + co * 32 + (ci & 31)] = f2bf(cw[co*512 + ci]);
    for (int l = 0; l < 5; ++l) {
        float g = gamma[l*256 + ci];
        float rs = rsqrtf(var[l*256 + ci] + 1e-5f);
        W2t[l*65536 + ci*256 + co] = cw[co*512 + 256 + ci] * g * rs;
    }
}

__global__ void prep_bias(const float* __restrict__ cw, const float* __restrict__ cb,
                          const float* __restrict__ gamma, const float* __restrict__ beta,
                          const float* __restrict__ mean, const float* __restrict__ var,
                          float* __restrict__ biasP)
{
    int l = blockIdx.x, co = threadIdx.x;
    float acc = cb[co];
    for (int ci = 0; ci < 256; ++ci) {
        float g = gamma[l*256+ci];
        float rs = rsqrtf(var[l*256+ci] + 1e-5f);
        float k = beta[l*256+ci] - g*rs*mean[l*256+ci];
        acc += cw[co*512 + 256 + ci] * k;
    }
    biasP[l*256 + co] = acc;
}

// ---------------- out = W1*f + bilerp(G)  -- bf16 MFMA GEMM -----------------
// grid: (ceil(HW/64), 2), block 256 (4 waves). M=256 co (64/wave), N=64 px, K=256.
__global__ __launch_bounds__(256) void out_mfma(
    const float* __restrict__ f, const unsigned short* __restrict__ W1s,
    const float* __restrict__ G, float* __restrict__ outp, int H, int W)
{
    __shared__ unsigned short ldsB[64 * 40];   // [px][ci] bf16, 80B row stride
    const int HW = H * W;
    const int p0 = blockIdx.x * 64;
    const int b  = blockIdx.y;
    const int t  = threadIdx.x;
    const int lane = t & 63;
    const int wid  = t >> 6;
    const int cw0  = wid * 64;
    const int l15  = lane & 15;
    const int g    = lane >> 4;

    f4acc acc[4][4];
    #pragma unroll
    for (int m = 0; m < 4; ++m)
        #pragma unroll
        for (int n = 0; n < 4; ++n)
            acc[m][n] = (f4acc){0.f, 0.f, 0.f, 0.f};

    const float* fb = f + (size_t)b * 256 * HW;
    const int px_st = t & 63;      // staging: this thread's px
    const int cg    = t >> 6;      // staging: 8-ci group

    for (int s = 0; s < 8; ++s) {
        __syncthreads();
        {
            int p = p0 + px_st;
            bool ok = p < HW;
            const float* src = fb + (size_t)(s * 32 + cg * 8) * HW + p;
            float v[8];
            #pragma unroll
            for (int e = 0; e < 8; ++e) v[e] = ok ? src[(size_t)e * HW] : 0.f;
            unsigned u[4];
            #pragma unroll
            for (int e = 0; e < 4; ++e)
                u[e] = (unsigned)f2bf(v[2*e]) | ((unsigned)f2bf(v[2*e+1]) << 16);
            *((uint4*)&ldsB[px_st * 40 + cg * 8]) = make_uint4(u[0], u[1], u[2], u[3]);
        }
        __syncthreads();
        bfrag a[4], bb[4];
        #pragma unroll
        for (int m = 0; m < 4; ++m)
            a[m] = *((const bfrag*)(W1s + (size_t)s * 8192 + (cw0 + m*16 + l15) * 32 + g * 8));
        #pragma unroll
        for (int n = 0; n < 4; ++n)
            bb[n] = *((const bfrag*)&ldsB[(n*16 + l15) * 40 + g * 8]);
        #pragma unroll
        for (int m = 0; m < 4; ++m)
            #pragma unroll
            for (int n = 0; n < 4; ++n)
                acc[m][n] = __builtin_amdgcn_mfma_f32_16x16x32_bf16(a[m], bb[n], acc[m][n], 0, 0, 0);
    }

    const int r0 = (lane >> 4) * 4;
    #pragma unroll
    for (int n = 0; n < 4; ++n) {
        int px = p0 + n*16 + l15;
        if (px >= HW) continue;
        int yy = px / W;
        int xx = px - yy * W;
        float ty = (float)(yy * 31) / (float)(H - 1);
        float tx = (float)(xx * 31) / (float)(W - 1);
        int y0 = (int)ty; float wy = ty - y0;
        int x0 = (int)tx; float wx = tx - x0;
        int y1 = min(y0 + 1, 31), x1 = min(x0 + 1, 31);
        float w00 = (1.f-wy)*(1.f-wx), w01 = (1.f-wy)*wx;
        float w10 = wy*(1.f-wx),       w11 = wy*wx;
        int i00 = y0*32+x0, i01 = y0*32+x1, i10 = y1*32+x0, i11 = y1*32+x1;
        #pragma unroll
        for (int m = 0; m < 4; ++m) {
            #pragma unroll
            for (int j = 0; j < 4; ++j) {
                int co = cw0 + m*16 + r0 + j;
                const float* gb = G + ((size_t)b*256 + co) * 1024;
                float gv = gb[i00]*w00 + gb[i01]*w01 + gb[i10]*w10 + gb[i11]*w11;
                outp[((size_t)b*256 + co) * HW + px] = acc[m][n][j] + gv;
            }
        }
    }
}

extern "C" void kernel_launch(void* const* d_in, const int* in_sizes, int n_in,
                              void* d_out, int out_size, void* d_ws, size_t ws_size,
                              hipStream_t stream)
{
    const float* f[5]; for (int i = 0; i < 5; ++i) f[i] = (const float*)d_in[i];
    const float* att   = (const float*)d_in[5];
    const float* ktw   = (const float*)d_in[6];
    const float* ktb   = (const float*)d_in[7];
    const float* vtw   = (const float*)d_in[8];
    const float* vtb   = (const float*)d_in[9];
    const float* kqw   = (const float*)d_in[10];
    const float* kqbb  = (const float*)d_in[11];
    const float* vqw   = (const float*)d_in[12];
    const float* vqb   = (const float*)d_in[13];
    const float* gamma = (const float*)d_in[14];
    const float* beta  = (const float*)d_in[15];
    const float* mean  = (const float*)d_in[16];
    const float* var   = (const float*)d_in[17];
    const float* cw    = (const float*)d_in[18];
    const float* cb    = (const float*)d_in[19];
    float* outp = (float*)d_out;

    float* ws    = (float*)d_ws;
    float* kt    = ws;                        // 491520
    float* vt    = kt   + 491520;             // 1966080
    float* vtT   = vt   + 1966080;            // 1966080
    unsigned short* W1s = (unsigned short*)(vtT + 1966080);  // 65536 ushort (32768 f)
    float* W2t   = vtT  + 1966080 + 32768;    // 327680
    float* biasP = W2t  + 327680;             // 1280
    float* fr    = biasP + 1280;              // 524288
    float* kqB   = fr   + 524288;             // 65536
    float* fin   = kqB  + 65536;              // 524288
    float* G     = fin  + 524288;             // 524288
    float* wTkt  = G    + 524288;             // 73728
    float* wTvt  = wTkt + 73728;              // 294912
    float* wTkq  = wTvt + 294912;             // 368640
    float* wTvq  = wTkq + 368640;             // 1474560

    prep_w<<<256, 256, 0, stream>>>(cw, gamma, var, W1s, W2t);
    prep_bias<<<5, 256, 0, stream>>>(cw, cb, gamma, beta, mean, var, biasP);
    transpose_w_k<<<dim3(288, 1),  256, 0, stream>>>(ktw, wTkt, 32);
    transpose_w_k<<<dim3(1152, 1), 256, 0, stream>>>(vtw, wTvt, 128);
    transpose_w_k<<<dim3(288, 5),  256, 0, stream>>>(kqw, wTkq, 32);
    transpose_w_k<<<dim3(1152, 5), 256, 0, stream>>>(vqw, wTvq, 128);

    init_bias_k<<<1920, 256, 0, stream>>>(kt, ktb, 1.f, 32, 32768, 491520);
    init_bias_k<<<7680, 256, 0, stream>>>(vt, vtb, 1.f, 128, 131072, 1966080);
    conv3x3_v2<<<dim3(4, 2, 60), 256, 0, stream>>>(att, wTkt, kt, 32, 32768, 1.f);
    conv3x3_v2<<<dim3(4, 8, 60), 256, 0, stream>>>(att, wTvt, vt, 128, 131072, 1.f);
    transpose_vt<<<dim3(32, 4, 15), 256, 0, stream>>>(vt, vtT);

    const int Hs[5] = {200,100,50,25,13};
    const int Ws[5] = {336,168,84,42,21};
    size_t ooff = 0;
    for (int l = 0; l < 5; ++l) {
        int H = Hs[l], W = Ws[l], HW = H*W;
        resize32<<<2048, 256, 0, stream>>>(f[l], fr, H, W);
        init_bias_k<<<256, 256, 0, stream>>>(kqB, kqbb + l*32, 1.f, 32, 32768, 65536);
        conv3x3_v2<<<dim3(4, 2, 8), 256, 0, stream>>>(fr, wTkq + (size_t)l*73728, kqB, 32, 32768, 1.f);
        hipMemsetAsync(fin, 0, (size_t)2*256*1024*sizeof(float), stream);
        init_bias_k<<<1024, 256, 0, stream>>>(fin, vqb + l*128, 15.f, 128, 262144, 262144);
        conv3x3_v2<<<dim3(4, 8, 8), 256, 0, stream>>>(fr, wTvq + (size_t)l*294912, fin, 128, 262144, 15.f);
        attn_kernel<<<dim3(128, 15, 2), 256, 0, stream>>>(kqB, kt, vtT, fin);
        g_kernel<<<2048, 256, 0, stream>>>(fin, W2t + l*65536, biasP + l*256, G);
        out_mfma<<<dim3((HW+63)/64, 2), 256, 0, stream>>>(f[l], W1s, G, outp + ooff, H, W);
        ooff += (size_t)2*256*HW;
    }
}

// Round 4
// 1901.604 us; speedup vs baseline: 4.1724x; 1.6498x over previous
//
#include <hip/hip_runtime.h>

typedef __attribute__((ext_vector_type(8))) short bfrag;
typedef __attribute__((ext_vector_type(4))) float f4acc;

__device__ inline unsigned short f2bf(float x) {
    unsigned u = __float_as_uint(x);
    unsigned r = (u + 0x7FFF + ((u >> 16) & 1)) >> 16;
    return (unsigned short)r;
}

// ---------------- weight transpose: w[oc][ic][3][3] -> wT[ic*9+k][oc] -------
__global__ __launch_bounds__(256) void transpose_w_k(
    const float* __restrict__ src, float* __restrict__ dst, int OC)
{
    int lev = blockIdx.y;
    const float* s = src + (size_t)lev * OC * 2304;
    float* d = dst + (size_t)lev * OC * 2304;
    int g = blockIdx.x * 256 + threadIdx.x;
    if (g < OC * 2304) {
        int oc = g / 2304;
        int rem = g - oc * 2304;           // ic*9 + k
        d[(size_t)rem * OC + oc] = s[g];
    }
}

// ---------------- init: out[n][c][s] = bias[c]*scale ------------------------
__global__ __launch_bounds__(256) void init_bias_k(
    float* __restrict__ out, const float* __restrict__ bias, float scale,
    int nch, int nstride, int total)
{
    int g = blockIdx.x * 256 + threadIdx.x;
    if (g >= total) return;
    int s = g & 1023;
    int rest = g >> 10;
    int c = rest % nch;
    int n = rest / nch;
    out[(size_t)n * nstride + c * 1024 + s] = bias[c] * scale;
}

// ---------------- conv3x3 on 32x32, IC-slice of 64, atomic accumulate -------
__global__ __launch_bounds__(256) void conv3x3_v2(
    const float* __restrict__ in, const float* __restrict__ wT,
    float* __restrict__ out, int OC, int ostride, float scale)
{
    __shared__ float plane[4 * 340];       // 4 ch x 10 rows x 34 cols
    __shared__ float wlds[576];            // 4 ch x 9 k x 16 oc
    const int t = threadIdx.x;
    const int y0 = blockIdx.x * 8;
    const int oc0 = blockIdx.y * 16;
    const int n = blockIdx.z >> 2;
    const int ic0 = (blockIdx.z & 3) * 64;

    const int ocg = t & 3;
    const int pxg = t >> 2;
    const int yl = pxg >> 3;
    const int x0l = (pxg & 7) * 4;

    float acc[4][4];
    #pragma unroll
    for (int j = 0; j < 4; ++j)
        #pragma unroll
        for (int i = 0; i < 4; ++i) acc[j][i] = 0.f;

    const size_t inbase = (size_t)n * 262144;

    for (int cs = 0; cs < 16; ++cs) {
        __syncthreads();
        #pragma unroll
        for (int i = 0; i < 6; ++i) {
            int lin = t + 256 * i;
            if (lin < 1360) {
                int ch = lin / 340, rem = lin - 340 * ch;
                int row = rem / 34, col = rem - 34 * row;
                int gy = y0 - 1 + row, gx = col - 1;
                float v = 0.f;
                if (gy >= 0 && gy < 32 && gx >= 0 && gx < 32)
                    v = in[inbase + (size_t)(ic0 + cs * 4 + ch) * 1024 + gy * 32 + gx];
                plane[ch * 340 + rem] = v;
            }
        }
        const size_t wTbase = (size_t)(ic0 + cs * 4) * 9 * OC + oc0;
        #pragma unroll
        for (int i = 0; i < 3; ++i) {
            int lin = t + 256 * i;
            if (lin < 576) {
                int oc = lin & 15, kk = lin >> 4;
                wlds[lin] = wT[wTbase + (size_t)kk * OC + oc];
            }
        }
        __syncthreads();
        #pragma unroll
        for (int ch = 0; ch < 4; ++ch) {
            float4 wr[9];
            #pragma unroll
            for (int k = 0; k < 9; ++k)
                wr[k] = *((const float4*)&wlds[(ch * 9 + k) * 16 + ocg * 4]);
            float r[3][6];
            #pragma unroll
            for (int dy = 0; dy < 3; ++dy)
                #pragma unroll
                for (int dx = 0; dx < 6; ++dx)
                    r[dy][dx] = plane[ch * 340 + (yl + dy) * 34 + x0l + dx];
            #pragma unroll
            for (int j = 0; j < 4; ++j)
                #pragma unroll
                for (int i = 0; i < 4; ++i) {
                    float s = acc[j][i];
                    #pragma unroll
                    for (int dy = 0; dy < 3; ++dy)
                        #pragma unroll
                        for (int dx = 0; dx < 3; ++dx) {
                            float wv;
                            const float4 w4 = wr[dy * 3 + dx];
                            wv = (j == 0) ? w4.x : (j == 1) ? w4.y : (j == 2) ? w4.z : w4.w;
                            s += r[dy][i + dx] * wv;
                        }
                    acc[j][i] = s;
                }
        }
    }
    #pragma unroll
    for (int j = 0; j < 4; ++j) {
        int oc = oc0 + ocg * 4 + j;
        #pragma unroll
        for (int i = 0; i < 4; ++i)
            atomicAdd(&out[(size_t)n * ostride + (size_t)oc * 1024 + (y0 + yl) * 32 + x0l + i],
                      acc[j][i] * scale);
    }
}

// ------- transpose+cast: in[z][32][M] f32 -> out[z][M][32] bf16 -------------
__global__ __launch_bounds__(256) void transpose_cast32(
    const float* __restrict__ in, unsigned short* __restrict__ out, int M)
{
    __shared__ float tile[32][33];
    const int z = blockIdx.z;
    const int m0 = blockIdx.x * 32;
    const int tx = threadIdx.x & 31;
    const int ty = threadIdx.x >> 5;
    const float* src = in + (size_t)z * 32 * M;
    for (int i = ty; i < 32; i += 8)
        tile[i][tx] = src[(size_t)i * M + m0 + tx];
    __syncthreads();
    unsigned short* dst = out + (size_t)z * M * 32;
    for (int i = ty; i < 32; i += 8)
        dst[(size_t)(m0 + i) * 32 + tx] = f2bf(tile[tx][i]);
}

// ------- elementwise cast f32 -> bf16 ---------------------------------------
__global__ __launch_bounds__(256) void cast_bf16(
    const float* __restrict__ in, unsigned short* __restrict__ out, int total)
{
    int g = blockIdx.x * 256 + threadIdx.x;
    if (g < total) out[g] = f2bf(in[g]);
}

// ---------------- bilinear (align-corners) resize f(H,W) -> fr(32,32) --------
__global__ __launch_bounds__(256) void resize32(
    const float* __restrict__ f, float* __restrict__ fr, int H, int W)
{
    int g = blockIdx.x * 256 + threadIdx.x;
    int s = g & 1023;
    int c = (g >> 10) & 255;
    int b = g >> 18;
    int oy = s >> 5, ox = s & 31;
    float ty = (float)(oy * (H-1)) / 31.0f;
    float tx = (float)(ox * (W-1)) / 31.0f;
    int y0 = (int)ty; float wy = ty - y0;
    int y1 = min(y0+1, H-1);
    int x0 = (int)tx; float wx = tx - x0;
    int x1 = min(x0+1, W-1);
    const float* p = f + ((size_t)b*256 + c) * (size_t)(H*W);
    float v00 = p[y0*W+x0], v01 = p[y0*W+x1];
    float v10 = p[y1*W+x0], v11 = p[y1*W+x1];
    fr[g] = (v00*(1.f-wx) + v01*wx)*(1.f-wy) + (v10*(1.f-wx) + v11*wx)*wy;
}

// ---------------- MFMA flash attention --------------------------------------
// grid (16 s-tiles of 64, 15 n, 2 b), block 256 (4 waves).
// Q=ktT16[n] (1024x32), K=kqT16[b] (1024x32), V=vt16[n] ([c][m]),
// softmax over m (no max-sub: |S|<~31 is safe in f32), out += sum over n.
__global__ __launch_bounds__(256) void attn_mfma(
    const unsigned short* __restrict__ kqT16,  // [2][1024][32]
    const unsigned short* __restrict__ ktT16,  // [15][1024][32]
    const unsigned short* __restrict__ vt16,   // [15][128][1024]
    float* __restrict__ fin)                   // [2][256][1024] ch128..255
{
    __shared__ unsigned short P[64 * 136];     // [s 64][m 128], stride 136 u16
    __shared__ float sums[64];
    const int t = threadIdx.x;
    const int w = t >> 6;
    const int lane = t & 63;
    const int l15 = lane & 15;
    const int g = lane >> 4;
    const int s0 = blockIdx.x * 64;
    const int n = blockIdx.y, b = blockIdx.z;

    // Q A-frag: rows s = s0 + w*16 + l15, k = cq = g*8..g*8+7
    const bfrag qa = *(const bfrag*)(ktT16 + ((size_t)n*1024 + s0 + w*16 + l15)*32 + g*8);

    f4acc oacc[8];
    #pragma unroll
    for (int ct = 0; ct < 8; ++ct) oacc[ct] = (f4acc){0.f,0.f,0.f,0.f};
    float rs[4] = {0.f, 0.f, 0.f, 0.f};

    const unsigned short* Kbase = kqT16 + (size_t)b * 32768;
    const unsigned short* Vbase = vt16 + (size_t)n * 131072;
    unsigned short* Pw = P + (w * 16) * 136;   // wave-private 16 rows

    for (int mt = 0; mt < 8; ++mt) {
        const int m0 = mt * 128;
        // S tile: rows s (16/wave), cols m0..m0+127
        f4acc sf[8];
        #pragma unroll
        for (int j = 0; j < 8; ++j) {
            bfrag kb = *(const bfrag*)(Kbase + (size_t)(m0 + j*16 + l15)*32 + g*8);
            sf[j] = __builtin_amdgcn_mfma_f32_16x16x32_bf16(qa, kb, (f4acc){0.f,0.f,0.f,0.f}, 0, 0, 0);
        }
        // exp, partial row sums, P -> LDS (bf16)
        #pragma unroll
        for (int j = 0; j < 8; ++j) {
            #pragma unroll
            for (int r = 0; r < 4; ++r) {
                float e = __expf(sf[j][r]);
                rs[r] += e;
                Pw[(g*4 + r)*136 + j*16 + l15] = f2bf(e);
            }
        }
        // PV: out^T[c][s] += V[c][m] . P[m][s]
        #pragma unroll
        for (int ct = 0; ct < 8; ++ct) {
            #pragma unroll
            for (int ks = 0; ks < 4; ++ks) {
                bfrag va = *(const bfrag*)(Vbase + (size_t)(ct*16 + l15)*1024 + m0 + ks*32 + g*8);
                bfrag pb = *(const bfrag*)(Pw + l15*136 + ks*32 + g*8);
                oacc[ct] = __builtin_amdgcn_mfma_f32_16x16x32_bf16(va, pb, oacc[ct], 0, 0, 0);
            }
        }
    }
    // total row sums: reduce across the 16 col-lanes of each group
    #pragma unroll
    for (int d = 1; d < 16; d <<= 1)
        #pragma unroll
        for (int r = 0; r < 4; ++r)
            rs[r] += __shfl_xor(rs[r], d, 64);
    if (l15 == 0) {
        #pragma unroll
        for (int r = 0; r < 4; ++r) sums[w*16 + g*4 + r] = rs[r];
    }
    float inv = 1.f / sums[w*16 + l15];        // wave-private row, in-wave ordering
    float* fb = fin + ((size_t)b*256 + 128)*1024 + s0 + w*16 + l15;
    #pragma unroll
    for (int ct = 0; ct < 8; ++ct)
        #pragma unroll
        for (int r = 0; r < 4; ++r)
            atomicAdd(fb + (size_t)(ct*16 + g*4 + r)*1024, oacc[ct][r] * inv);
}

// ---------------- G = W2' * fin32 + bias'   (32x32 resolution conv1x1) ------
__global__ __launch_bounds__(256) void g_kernel(
    const float* __restrict__ fin, const float* __restrict__ W2t,
    const float* __restrict__ biasP, float* __restrict__ G)
{
    __shared__ float fv[256];
    int s = blockIdx.x & 1023;
    int b = blockIdx.x >> 10;
    int co = threadIdx.x;
    fv[co] = fin[((size_t)b*256 + co)*1024 + s];
    __syncthreads();
    float acc = biasP[co];
    #pragma unroll 8
    for (int ci = 0; ci < 256; ++ci)
        acc += W2t[ci*256 + co] * fv[ci];
    G[((size_t)b*256 + co)*1024 + s] = acc;
}

// -------- weight prep: W1 -> bf16 packed [kstep][co][32]; fold BN into W2 ---
__global__ void prep_w(const float* __restrict__ cw, const float* __restrict__ gamma,
                       const float* __restrict__ var, unsigned short* __restrict__ W1s,
                       float* __restrict__ W2t)
{
    int ci = blockIdx.x, co = threadIdx.x;
    W1s[(ci >> 5) * 8192 + co * 32 + (ci & 31)] = f2bf(cw[co*512 + ci]);
    for (int l = 0; l < 5; ++l) {
        float g = gamma[l*256 + ci];
        float rs = rsqrtf(var[l*256 + ci] + 1e-5f);
        W2t[l*65536 + ci*256 + co] = cw[co*512 + 256 + ci] * g * rs;
    }
}

__global__ void prep_bias(const float* __restrict__ cw, const float* __restrict__ cb,
                          const float* __restrict__ gamma, const float* __restrict__ beta,
                          const float* __restrict__ mean, const float* __restrict__ var,
                          float* __restrict__ biasP)
{
    int l = blockIdx.x, co = threadIdx.x;
    float acc = cb[co];
    for (int ci = 0; ci < 256; ++ci) {
        float g = gamma[l*256+ci];
        float rs = rsqrtf(var[l*256+ci] + 1e-5f);
        float k = beta[l*256+ci] - g*rs*mean[l*256+ci];
        acc += cw[co*512 + 256 + ci] * k;
    }
    biasP[l*256 + co] = acc;
}

// ---------------- out = W1*f + bilerp(G)  -- bf16 MFMA GEMM -----------------
__global__ __launch_bounds__(256) void out_mfma(
    const float* __restrict__ f, const unsigned short* __restrict__ W1s,
    const float* __restrict__ G, float* __restrict__ outp, int H, int W)
{
    __shared__ unsigned short ldsB[64 * 40];   // [px][ci] bf16, 80B row stride
    const int HW = H * W;
    const int p0 = blockIdx.x * 64;
    const int b  = blockIdx.y;
    const int t  = threadIdx.x;
    const int lane = t & 63;
    const int wid  = t >> 6;
    const int cw0  = wid * 64;
    const int l15  = lane & 15;
    const int g    = lane >> 4;

    f4acc acc[4][4];
    #pragma unroll
    for (int m = 0; m < 4; ++m)
        #pragma unroll
        for (int n = 0; n < 4; ++n)
            acc[m][n] = (f4acc){0.f, 0.f, 0.f, 0.f};

    const float* fb = f + (size_t)b * 256 * HW;
    const int px_st = t & 63;
    const int cg    = t >> 6;

    for (int s = 0; s < 8; ++s) {
        __syncthreads();
        {
            int p = p0 + px_st;
            bool ok = p < HW;
            const float* src = fb + (size_t)(s * 32 + cg * 8) * HW + p;
            float v[8];
            #pragma unroll
            for (int e = 0; e < 8; ++e) v[e] = ok ? src[(size_t)e * HW] : 0.f;
            unsigned u[4];
            #pragma unroll
            for (int e = 0; e < 4; ++e)
                u[e] = (unsigned)f2bf(v[2*e]) | ((unsigned)f2bf(v[2*e+1]) << 16);
            *((uint4*)&ldsB[px_st * 40 + cg * 8]) = make_uint4(u[0], u[1], u[2], u[3]);
        }
        __syncthreads();
        bfrag a[4], bb[4];
        #pragma unroll
        for (int m = 0; m < 4; ++m)
            a[m] = *((const bfrag*)(W1s + (size_t)s * 8192 + (cw0 + m*16 + l15) * 32 + g * 8));
        #pragma unroll
        for (int n = 0; n < 4; ++n)
            bb[n] = *((const bfrag*)&ldsB[(n*16 + l15) * 40 + g * 8]);
        #pragma unroll
        for (int m = 0; m < 4; ++m)
            #pragma unroll
            for (int n = 0; n < 4; ++n)
                acc[m][n] = __builtin_amdgcn_mfma_f32_16x16x32_bf16(a[m], bb[n], acc[m][n], 0, 0, 0);
    }

    const int r0 = (lane >> 4) * 4;
    #pragma unroll
    for (int n = 0; n < 4; ++n) {
        int px = p0 + n*16 + l15;
        if (px >= HW) continue;
        int yy = px / W;
        int xx = px - yy * W;
        float ty = (float)(yy * 31) / (float)(H - 1);
        float tx = (float)(xx * 31) / (float)(W - 1);
        int y0 = (int)ty; float wy = ty - y0;
        int x0 = (int)tx; float wx = tx - x0;
        int y1 = min(y0 + 1, 31), x1 = min(x0 + 1, 31);
        float w00 = (1.f-wy)*(1.f-wx), w01 = (1.f-wy)*wx;
        float w10 = wy*(1.f-wx),       w11 = wy*wx;
        int i00 = y0*32+x0, i01 = y0*32+x1, i10 = y1*32+x0, i11 = y1*32+x1;
        #pragma unroll
        for (int m = 0; m < 4; ++m) {
            #pragma unroll
            for (int j = 0; j < 4; ++j) {
                int co = cw0 + m*16 + r0 + j;
                const float* gb = G + ((size_t)b*256 + co) * 1024;
                float gv = gb[i00]*w00 + gb[i01]*w01 + gb[i10]*w10 + gb[i11]*w11;
                outp[((size_t)b*256 + co) * HW + px] = acc[m][n][j] + gv;
            }
        }
    }
}

extern "C" void kernel_launch(void* const* d_in, const int* in_sizes, int n_in,
                              void* d_out, int out_size, void* d_ws, size_t ws_size,
                              hipStream_t stream)
{
    const float* f[5]; for (int i = 0; i < 5; ++i) f[i] = (const float*)d_in[i];
    const float* att   = (const float*)d_in[5];
    const float* ktw   = (const float*)d_in[6];
    const float* ktb   = (const float*)d_in[7];
    const float* vtw   = (const float*)d_in[8];
    const float* vtb   = (const float*)d_in[9];
    const float* kqw   = (const float*)d_in[10];
    const float* kqbb  = (const float*)d_in[11];
    const float* vqw   = (const float*)d_in[12];
    const float* vqb   = (const float*)d_in[13];
    const float* gamma = (const float*)d_in[14];
    const float* beta  = (const float*)d_in[15];
    const float* mean  = (const float*)d_in[16];
    const float* var   = (const float*)d_in[17];
    const float* cw    = (const float*)d_in[18];
    const float* cb    = (const float*)d_in[19];
    float* outp = (float*)d_out;

    float* ws    = (float*)d_ws;
    float* kt    = ws;                          // 491520
    float* vt    = kt + 491520;                 // 1966080
    unsigned short* ktT16 = (unsigned short*)(vt + 1966080);   // 491520 u16
    unsigned short* kqT16 = ktT16 + 491520;                    // 65536 u16
    unsigned short* vt16  = kqT16 + 65536;                     // 1966080 u16
    unsigned short* W1s   = vt16 + 1966080;                    // 65536 u16
    float* W2t   = (float*)(W1s + 65536);       // 327680
    float* biasP = W2t + 327680;                // 1280
    float* fr    = biasP + 1280;                // 524288
    float* kqB   = fr + 524288;                 // 65536
    float* fin   = kqB + 65536;                 // 524288
    float* G     = fin + 524288;                // 524288
    float* wTkt  = G + 524288;                  // 73728
    float* wTvt  = wTkt + 73728;                // 294912
    float* wTkq  = wTvt + 294912;               // 368640
    float* wTvq  = wTkq + 368640;               // 1474560

    prep_w<<<256, 256, 0, stream>>>(cw, gamma, var, W1s, W2t);
    prep_bias<<<5, 256, 0, stream>>>(cw, cb, gamma, beta, mean, var, biasP);
    transpose_w_k<<<dim3(288, 1),  256, 0, stream>>>(ktw, wTkt, 32);
    transpose_w_k<<<dim3(1152, 1), 256, 0, stream>>>(vtw, wTvt, 128);
    transpose_w_k<<<dim3(288, 5),  256, 0, stream>>>(kqw, wTkq, 32);
    transpose_w_k<<<dim3(1152, 5), 256, 0, stream>>>(vqw, wTvq, 128);

    init_bias_k<<<1920, 256, 0, stream>>>(kt, ktb, 1.f, 32, 32768, 491520);
    init_bias_k<<<7680, 256, 0, stream>>>(vt, vtb, 1.f, 128, 131072, 1966080);
    conv3x3_v2<<<dim3(4, 2, 60), 256, 0, stream>>>(att, wTkt, kt, 32, 32768, 1.f);
    conv3x3_v2<<<dim3(4, 8, 60), 256, 0, stream>>>(att, wTvt, vt, 128, 131072, 1.f);
    transpose_cast32<<<dim3(32, 1, 15), 256, 0, stream>>>(kt, ktT16, 1024);
    cast_bf16<<<7680, 256, 0, stream>>>(vt, vt16, 1966080);

    const int Hs[5] = {200,100,50,25,13};
    const int Ws[5] = {336,168,84,42,21};
    size_t ooff = 0;
    for (int l = 0; l < 5; ++l) {
        int H = Hs[l], W = Ws[l], HW = H*W;
        resize32<<<2048, 256, 0, stream>>>(f[l], fr, H, W);
        init_bias_k<<<256, 256, 0, stream>>>(kqB, kqbb + l*32, 1.f, 32, 32768, 65536);
        conv3x3_v2<<<dim3(4, 2, 8), 256, 0, stream>>>(fr, wTkq + (size_t)l*73728, kqB, 32, 32768, 1.f);
        transpose_cast32<<<dim3(32, 1, 2), 256, 0, stream>>>(kqB, kqT16, 1024);
        hipMemsetAsync(fin, 0, (size_t)2*256*1024*sizeof(float), stream);
        init_bias_k<<<1024, 256, 0, stream>>>(fin, vqb + l*128, 15.f, 128, 262144, 262144);
        conv3x3_v2<<<dim3(4, 8, 8), 256, 0, stream>>>(fr, wTvq + (size_t)l*294912, fin, 128, 262144, 15.f);
        attn_mfma<<<dim3(16, 15, 2), 256, 0, stream>>>(kqT16, ktT16, vt16, fin);
        g_kernel<<<2048, 256, 0, stream>>>(fin, W2t + l*65536, biasP + l*256, G);
        out_mfma<<<dim3((HW+63)/64, 2), 256, 0, stream>>>(f[l], W1s, G, outp + ooff, H, W);
        ooff += (size_t)2*256*HW;
    }
}

// Round 5
// 1076.476 us; speedup vs baseline: 7.3705x; 1.7665x over previous
//
#include <hip/hip_runtime.h>

typedef __attribute__((ext_vector_type(8))) short bfrag;
typedef __attribute__((ext_vector_type(4))) float f4acc;

__device__ inline unsigned short f2bf(float x) {
    unsigned u = __float_as_uint(x);
    unsigned r = (u + 0x7FFF + ((u >> 16) & 1)) >> 16;
    return (unsigned short)r;
}

// -------- pack conv weights: w[lev][OC][256][3][3] -> Wp[lev][9][OC][256] bf16
__global__ __launch_bounds__(256) void pack_w(
    const float* __restrict__ src, unsigned short* __restrict__ dst, int OC)
{
    const int lev = blockIdx.y;
    const int tot = OC * 2304;
    int g = blockIdx.x * 256 + threadIdx.x;
    if (g >= tot) return;
    int ic = g & 255;
    int rest = g >> 8;
    int oc = rest % OC;
    int tap = rest / OC;
    dst[(size_t)lev * tot + g] = f2bf(src[(size_t)lev * tot + ((size_t)oc * 256 + ic) * 9 + tap]);
}

// -------- conv3x3 as 9-tap implicit GEMM, bf16 MFMA ------------------------
// grid (8 px-tiles of 128, n_img), block 256 (4 waves).
// in: [img][256][1024] f32. Wp: [lev][9][OC][256] bf16. K-loop: 9 taps x 8 ic-steps.
// MODE 0: f32 out[img][OC][1024] (stride 262144, ch0..OC-1), *scale
// MODE 1: bf16 out[img][1024][OC]  (transposed, for attn K/Q operands)
// MODE 2: bf16 out[img][OC][1024]  (for attn V operand)
template<int OC, int MODE>
__global__ __launch_bounds__(256) void convgemm(
    const float* __restrict__ in, const unsigned short* __restrict__ Wp,
    int w_lstride, const float* __restrict__ bias, int b_lstride,
    void* __restrict__ outp, float scale)
{
    __shared__ unsigned short ldsB[128 * 40];   // [px][ic_local], stride 40 u16
    const int t = threadIdx.x;
    const int img = blockIdx.y;
    const int p0 = blockIdx.x * 128;
    const int lane = t & 63, w = t >> 6, l15 = lane & 15, g = lane >> 4;
    constexpr int MF = (OC == 128) ? 4 : 2;
    constexpr int NF = (OC == 128) ? 4 : 2;
    constexpr int WN = (OC == 128) ? 2 : 4;
    const int wm = w / WN, wn = w % WN;
    const int oc0w = wm * MF * 16;
    const int px0w = wn * NF * 16;
    const unsigned short* Wb = Wp + (size_t)(img >> 1) * w_lstride;
    const float* bb = bias + (img >> 1) * b_lstride;
    const float* inb = in + (size_t)img * 262144;

    const int px_l = t & 127;
    const int icg = t >> 7;        // 0..1
    const int pxg = p0 + px_l;
    const int y = pxg >> 5, x = pxg & 31;

    f4acc acc[MF][NF];
    #pragma unroll
    for (int m = 0; m < MF; ++m)
        #pragma unroll
        for (int n = 0; n < NF; ++n) acc[m][n] = (f4acc){0.f, 0.f, 0.f, 0.f};

    for (int tap = 0; tap < 9; ++tap) {
        const int dy = tap / 3 - 1, dx = tap % 3 - 1;
        const int sy = y + dy, sx = x + dx;
        const bool ok = ((unsigned)sy < 32u) && ((unsigned)sx < 32u);
        const int soff = ok ? (sy * 32 + sx) : 0;
        const unsigned short* Wtap = Wb + (size_t)tap * OC * 256;
        for (int ics = 0; ics < 8; ++ics) {
            const int ic0 = ics * 32;
            __syncthreads();
            {
                const float* src = inb + (size_t)(ic0 + icg * 16) * 1024 + soff;
                unsigned uu[8];
                #pragma unroll
                for (int e = 0; e < 8; ++e) {
                    float v0 = src[(size_t)(2 * e) * 1024];
                    float v1 = src[(size_t)(2 * e + 1) * 1024];
                    v0 = ok ? v0 : 0.f;
                    v1 = ok ? v1 : 0.f;
                    uu[e] = (unsigned)f2bf(v0) | ((unsigned)f2bf(v1) << 16);
                }
                *((uint4*)&ldsB[px_l * 40 + icg * 16])     = make_uint4(uu[0], uu[1], uu[2], uu[3]);
                *((uint4*)&ldsB[px_l * 40 + icg * 16 + 8]) = make_uint4(uu[4], uu[5], uu[6], uu[7]);
            }
            __syncthreads();
            bfrag a[MF], bf[NF];
            #pragma unroll
            for (int m = 0; m < MF; ++m)
                a[m] = *((const bfrag*)(Wtap + (size_t)(oc0w + m * 16 + l15) * 256 + ic0 + g * 8));
            #pragma unroll
            for (int n = 0; n < NF; ++n)
                bf[n] = *((const bfrag*)&ldsB[(px0w + n * 16 + l15) * 40 + g * 8]);
            #pragma unroll
            for (int m = 0; m < MF; ++m)
                #pragma unroll
                for (int n = 0; n < NF; ++n)
                    acc[m][n] = __builtin_amdgcn_mfma_f32_16x16x32_bf16(a[m], bf[n], acc[m][n], 0, 0, 0);
        }
    }
    // epilogue: C row = oc (A), col = px (B); row = g*4 + j
    #pragma unroll
    for (int m = 0; m < MF; ++m) {
        #pragma unroll
        for (int n = 0; n < NF; ++n) {
            const int px = p0 + px0w + n * 16 + l15;
            #pragma unroll
            for (int j = 0; j < 4; ++j) {
                const int oc = oc0w + m * 16 + g * 4 + j;
                float val = acc[m][n][j] + bb[oc];
                if (MODE == 0)
                    ((float*)outp)[(size_t)img * 262144 + (size_t)oc * 1024 + px] = val * scale;
                else if (MODE == 1)
                    ((unsigned short*)outp)[((size_t)img * 1024 + px) * OC + oc] = f2bf(val);
                else
                    ((unsigned short*)outp)[(size_t)img * OC * 1024 + (size_t)oc * 1024 + px] = f2bf(val);
            }
        }
    }
}

// ---------------- bilinear (align-corners) resize f(H,W) -> fr(32,32) --------
__global__ __launch_bounds__(256) void resize32(
    const float* __restrict__ f, float* __restrict__ fr, int H, int W)
{
    int g = blockIdx.x * 256 + threadIdx.x;
    int s = g & 1023;
    int c = (g >> 10) & 255;
    int b = g >> 18;
    int oy = s >> 5, ox = s & 31;
    float ty = (float)(oy * (H-1)) / 31.0f;
    float tx = (float)(ox * (W-1)) / 31.0f;
    int y0 = (int)ty; float wy = ty - y0;
    int y1 = min(y0+1, H-1);
    int x0 = (int)tx; float wx = tx - x0;
    int x1 = min(x0+1, W-1);
    const float* p = f + ((size_t)b*256 + c) * (size_t)(H*W);
    float v00 = p[y0*W+x0], v01 = p[y0*W+x1];
    float v10 = p[y1*W+x0], v11 = p[y1*W+x1];
    fr[g] = (v00*(1.f-wx) + v01*wx)*(1.f-wy) + (v10*(1.f-wx) + v11*wx)*wy;
}

// ---------------- MFMA flash attention, batched over (lev,b) ----------------
// grid (16 s-tiles of 64, 15 n, 10 z=lev*2+b), block 256 (4 waves).
__global__ __launch_bounds__(256) void attn_mfma(
    const unsigned short* __restrict__ kqT16,  // [10][1024][32]
    const unsigned short* __restrict__ ktT16,  // [15][1024][32]
    const unsigned short* __restrict__ vt16,   // [15][128][1024]
    float* __restrict__ fin)                   // [10][256][1024] ch128..255
{
    __shared__ unsigned short P[64 * 136];
    __shared__ float sums[64];
    const int t = threadIdx.x;
    const int w = t >> 6;
    const int lane = t & 63;
    const int l15 = lane & 15;
    const int g = lane >> 4;
    const int s0 = blockIdx.x * 64;
    const int n = blockIdx.y, z = blockIdx.z;

    const bfrag qa = *(const bfrag*)(ktT16 + ((size_t)n*1024 + s0 + w*16 + l15)*32 + g*8);

    f4acc oacc[8];
    #pragma unroll
    for (int ct = 0; ct < 8; ++ct) oacc[ct] = (f4acc){0.f,0.f,0.f,0.f};
    float rs[4] = {0.f, 0.f, 0.f, 0.f};

    const unsigned short* Kbase = kqT16 + (size_t)z * 32768;
    const unsigned short* Vbase = vt16 + (size_t)n * 131072;
    unsigned short* Pw = P + (w * 16) * 136;

    for (int mt = 0; mt < 8; ++mt) {
        const int m0 = mt * 128;
        f4acc sf[8];
        #pragma unroll
        for (int j = 0; j < 8; ++j) {
            bfrag kb = *(const bfrag*)(Kbase + (size_t)(m0 + j*16 + l15)*32 + g*8);
            sf[j] = __builtin_amdgcn_mfma_f32_16x16x32_bf16(qa, kb, (f4acc){0.f,0.f,0.f,0.f}, 0, 0, 0);
        }
        #pragma unroll
        for (int j = 0; j < 8; ++j) {
            #pragma unroll
            for (int r = 0; r < 4; ++r) {
                float e = __expf(sf[j][r]);
                rs[r] += e;
                Pw[(g*4 + r)*136 + j*16 + l15] = f2bf(e);
            }
        }
        #pragma unroll
        for (int ct = 0; ct < 8; ++ct) {
            #pragma unroll
            for (int ks = 0; ks < 4; ++ks) {
                bfrag va = *(const bfrag*)(Vbase + (size_t)(ct*16 + l15)*1024 + m0 + ks*32 + g*8);
                bfrag pb = *(const bfrag*)(Pw + l15*136 + ks*32 + g*8);
                oacc[ct] = __builtin_amdgcn_mfma_f32_16x16x32_bf16(va, pb, oacc[ct], 0, 0, 0);
            }
        }
    }
    #pragma unroll
    for (int d = 1; d < 16; d <<= 1)
        #pragma unroll
        for (int r = 0; r < 4; ++r)
            rs[r] += __shfl_xor(rs[r], d, 64);
    if (l15 == 0) {
        #pragma unroll
        for (int r = 0; r < 4; ++r) sums[w*16 + g*4 + r] = rs[r];
    }
    float inv = 1.f / sums[w*16 + l15];
    float* fb = fin + ((size_t)z*256 + 128)*1024 + s0 + w*16 + l15;
    #pragma unroll
    for (int ct = 0; ct < 8; ++ct)
        #pragma unroll
        for (int r = 0; r < 4; ++r)
            atomicAdd(fb + (size_t)(ct*16 + g*4 + r)*1024, oacc[ct][r] * inv);
}

// ---------------- G = W2' * fin + bias', batched over levels ----------------
__global__ __launch_bounds__(256) void g_kernel(
    const float* __restrict__ fin5, const float* __restrict__ W2t,
    const float* __restrict__ biasP, float* __restrict__ G5)
{
    __shared__ float fv[256];
    const int lev = blockIdx.y;
    int s = blockIdx.x & 1023;
    int b = blockIdx.x >> 10;
    int co = threadIdx.x;
    const float* fin = fin5 + (size_t)lev * 524288;
    fv[co] = fin[((size_t)b*256 + co)*1024 + s];
    __syncthreads();
    float acc = biasP[lev*256 + co];
    const float* W2 = W2t + (size_t)lev * 65536;
    #pragma unroll 8
    for (int ci = 0; ci < 256; ++ci)
        acc += W2[ci*256 + co] * fv[ci];
    G5[(size_t)lev * 524288 + ((size_t)b*256 + co)*1024 + s] = acc;
}

// -------- weight prep: W1 -> bf16 packed [kstep][co][32]; fold BN into W2 ---
__global__ void prep_w(const float* __restrict__ cw, const float* __restrict__ gamma,
                       const float* __restrict__ var, unsigned short* __restrict__ W1s,
                       float* __restrict__ W2t)
{
    int ci = blockIdx.x, co = threadIdx.x;
    W1s[(ci >> 5) * 8192 + co * 32 + (ci & 31)] = f2bf(cw[co*512 + ci]);
    for (int l = 0; l < 5; ++l) {
        float g = gamma[l*256 + ci];
        float rs = rsqrtf(var[l*256 + ci] + 1e-5f);
        W2t[l*65536 + ci*256 + co] = cw[co*512 + 256 + ci] * g * rs;
    }
}

__global__ void prep_bias(const float* __restrict__ cw, const float* __restrict__ cb,
                          const float* __restrict__ gamma, const float* __restrict__ beta,
                          const float* __restrict__ mean, const float* __restrict__ var,
                          float* __restrict__ biasP)
{
    int l = blockIdx.x, co = threadIdx.x;
    float acc = cb[co];
    for (int ci = 0; ci < 256; ++ci) {
        float g = gamma[l*256+ci];
        float rs = rsqrtf(var[l*256+ci] + 1e-5f);
        float k = beta[l*256+ci] - g*rs*mean[l*256+ci];
        acc += cw[co*512 + 256 + ci] * k;
    }
    biasP[l*256 + co] = acc;
}

// ---------------- out = W1*f + bilerp(G)  -- bf16 MFMA GEMM -----------------
__global__ __launch_bounds__(256) void out_mfma(
    const float* __restrict__ f, const unsigned short* __restrict__ W1s,
    const float* __restrict__ G, float* __restrict__ outp, int H, int W)
{
    __shared__ unsigned short ldsB[64 * 40];
    const int HW = H * W;
    const int p0 = blockIdx.x * 64;
    const int b  = blockIdx.y;
    const int t  = threadIdx.x;
    const int lane = t & 63;
    const int wid  = t >> 6;
    const int cw0  = wid * 64;
    const int l15  = lane & 15;
    const int g    = lane >> 4;

    f4acc acc[4][4];
    #pragma unroll
    for (int m = 0; m < 4; ++m)
        #pragma unroll
        for (int n = 0; n < 4; ++n)
            acc[m][n] = (f4acc){0.f, 0.f, 0.f, 0.f};

    const float* fb = f + (size_t)b * 256 * HW;
    const int px_st = t & 63;
    const int cg    = t >> 6;

    for (int s = 0; s < 8; ++s) {
        __syncthreads();
        {
            int p = p0 + px_st;
            bool ok = p < HW;
            const float* src = fb + (size_t)(s * 32 + cg * 8) * HW + p;
            float v[8];
            #pragma unroll
            for (int e = 0; e < 8; ++e) v[e] = ok ? src[(size_t)e * HW] : 0.f;
            unsigned u[4];
            #pragma unroll
            for (int e = 0; e < 4; ++e)
                u[e] = (unsigned)f2bf(v[2*e]) | ((unsigned)f2bf(v[2*e+1]) << 16);
            *((uint4*)&ldsB[px_st * 40 + cg * 8]) = make_uint4(u[0], u[1], u[2], u[3]);
        }
        __syncthreads();
        bfrag a[4], bb[4];
        #pragma unroll
        for (int m = 0; m < 4; ++m)
            a[m] = *((const bfrag*)(W1s + (size_t)s * 8192 + (cw0 + m*16 + l15) * 32 + g * 8));
        #pragma unroll
        for (int n = 0; n < 4; ++n)
            bb[n] = *((const bfrag*)&ldsB[(n*16 + l15) * 40 + g * 8]);
        #pragma unroll
        for (int m = 0; m < 4; ++m)
            #pragma unroll
            for (int n = 0; n < 4; ++n)
                acc[m][n] = __builtin_amdgcn_mfma_f32_16x16x32_bf16(a[m], bb[n], acc[m][n], 0, 0, 0);
    }

    const int r0 = (lane >> 4) * 4;
    #pragma unroll
    for (int n = 0; n < 4; ++n) {
        int px = p0 + n*16 + l15;
        if (px >= HW) continue;
        int yy = px / W;
        int xx = px - yy * W;
        float ty = (float)(yy * 31) / (float)(H - 1);
        float tx = (float)(xx * 31) / (float)(W - 1);
        int y0 = (int)ty; float wy = ty - y0;
        int x0 = (int)tx; float wx = tx - x0;
        int y1 = min(y0 + 1, 31), x1 = min(x0 + 1, 31);
        float w00 = (1.f-wy)*(1.f-wx), w01 = (1.f-wy)*wx;
        float w10 = wy*(1.f-wx),       w11 = wy*wx;
        int i00 = y0*32+x0, i01 = y0*32+x1, i10 = y1*32+x0, i11 = y1*32+x1;
        #pragma unroll
        for (int m = 0; m < 4; ++m) {
            #pragma unroll
            for (int j = 0; j < 4; ++j) {
                int co = cw0 + m*16 + r0 + j;
                const float* gb = G + ((size_t)b*256 + co) * 1024;
                float gv = gb[i00]*w00 + gb[i01]*w01 + gb[i10]*w10 + gb[i11]*w11;
                outp[((size_t)b*256 + co) * HW + px] = acc[m][n][j] + gv;
            }
        }
    }
}

extern "C" void kernel_launch(void* const* d_in, const int* in_sizes, int n_in,
                              void* d_out, int out_size, void* d_ws, size_t ws_size,
                              hipStream_t stream)
{
    const float* f[5]; for (int i = 0; i < 5; ++i) f[i] = (const float*)d_in[i];
    const float* att   = (const float*)d_in[5];
    const float* ktw   = (const float*)d_in[6];
    const float* ktb   = (const float*)d_in[7];
    const float* vtw   = (const float*)d_in[8];
    const float* vtb   = (const float*)d_in[9];
    const float* kqw   = (const float*)d_in[10];
    const float* kqbb  = (const float*)d_in[11];
    const float* vqw   = (const float*)d_in[12];
    const float* vqb   = (const float*)d_in[13];
    const float* gamma = (const float*)d_in[14];
    const float* beta  = (const float*)d_in[15];
    const float* mean  = (const float*)d_in[16];
    const float* var   = (const float*)d_in[17];
    const float* cw    = (const float*)d_in[18];
    const float* cb    = (const float*)d_in[19];
    float* outp = (float*)d_out;

    unsigned short* ktT16 = (unsigned short*)d_ws;      // 491520
    unsigned short* kqT16 = ktT16 + 491520;             // 327680
    unsigned short* vt16  = kqT16 + 327680;             // 1966080
    unsigned short* wpkt  = vt16 + 1966080;             // 73728
    unsigned short* wpvt  = wpkt + 73728;               // 294912
    unsigned short* wpkq  = wpvt + 294912;              // 368640
    unsigned short* wpvq  = wpkq + 368640;              // 1474560
    unsigned short* W1s   = wpvq + 1474560;             // 65536
    float* W2t   = (float*)(W1s + 65536);               // 327680 f
    float* biasP = W2t + 327680;                        // 1280
    float* fr5   = biasP + 1280;                        // 2621440
    float* fin5  = fr5 + 2621440;                       // 2621440
    float* G5    = fin5 + 2621440;                      // 2621440

    prep_w<<<256, 256, 0, stream>>>(cw, gamma, var, W1s, W2t);
    prep_bias<<<5, 256, 0, stream>>>(cw, cb, gamma, beta, mean, var, biasP);
    pack_w<<<dim3(288, 1),  256, 0, stream>>>(ktw, wpkt, 32);
    pack_w<<<dim3(1152, 1), 256, 0, stream>>>(vtw, wpvt, 128);
    pack_w<<<dim3(288, 5),  256, 0, stream>>>(kqw, wpkq, 32);
    pack_w<<<dim3(1152, 5), 256, 0, stream>>>(vqw, wpvq, 128);

    // template convs: kt (bf16 transposed), vt (bf16 [c][m])
    convgemm<32, 1><<<dim3(8, 15), 256, 0, stream>>>(att, wpkt, 0, ktb, 0, ktT16, 1.f);
    convgemm<128, 2><<<dim3(8, 15), 256, 0, stream>>>(att, wpvt, 0, vtb, 0, vt16, 1.f);

    const int Hs[5] = {200,100,50,25,13};
    const int Ws[5] = {336,168,84,42,21};
    for (int l = 0; l < 5; ++l)
        resize32<<<2048, 256, 0, stream>>>(f[l], fr5 + (size_t)l*524288, Hs[l], Ws[l]);

    hipMemsetAsync(fin5, 0, (size_t)2621440 * sizeof(float), stream);
    convgemm<32, 1><<<dim3(8, 10), 256, 0, stream>>>(fr5, wpkq, 73728, kqbb, 32, kqT16, 1.f);
    convgemm<128, 0><<<dim3(8, 10), 256, 0, stream>>>(fr5, wpvq, 294912, vqb, 128, fin5, 15.f);

    attn_mfma<<<dim3(16, 15, 10), 256, 0, stream>>>(kqT16, ktT16, vt16, fin5);
    g_kernel<<<dim3(2048, 5), 256, 0, stream>>>(fin5, W2t, biasP, G5);

    size_t ooff = 0;
    for (int l = 0; l < 5; ++l) {
        int H = Hs[l], W = Ws[l], HW = H*W;
        out_mfma<<<dim3((HW+63)/64, 2), 256, 0, stream>>>(f[l], W1s, G5 + (size_t)l*524288, outp + ooff, H, W);
        ooff += (size_t)2*256*HW;
    }
}

// Round 6
// 1075.845 us; speedup vs baseline: 7.3749x; 1.0006x over previous
//
#include <hip/hip_runtime.h>

typedef __attribute__((ext_vector_type(8))) short bfrag;
typedef __attribute__((ext_vector_type(4))) float f4acc;

__device__ inline unsigned short f2bf(float x) {
    unsigned u = __float_as_uint(x);
    unsigned r = (u + 0x7FFF + ((u >> 16) & 1)) >> 16;
    return (unsigned short)r;
}
__device__ inline float bf2f(unsigned short h) {
    unsigned u = ((unsigned)h) << 16;
    return __uint_as_float(u);
}

// -------- pack conv weights: w[lev][OC][256][3][3] -> Wp[lev][9][OC][256] bf16
__global__ __launch_bounds__(256) void pack_w(
    const float* __restrict__ src, unsigned short* __restrict__ dst, int OC)
{
    const int lev = blockIdx.y;
    const int tot = OC * 2304;
    int g = blockIdx.x * 256 + threadIdx.x;
    if (g >= tot) return;
    int ic = g & 255;
    int rest = g >> 8;
    int oc = rest % OC;
    int tap = rest / OC;
    dst[(size_t)lev * tot + g] = f2bf(src[(size_t)lev * tot + ((size_t)oc * 256 + ic) * 9 + tap]);
}

// -------- conv3x3 as 9-tap implicit GEMM, bf16 MFMA ------------------------
template<int OC, int MODE>
__global__ __launch_bounds__(256) void convgemm(
    const float* __restrict__ in, const unsigned short* __restrict__ Wp,
    int w_lstride, const float* __restrict__ bias, int b_lstride,
    void* __restrict__ outp, float scale)
{
    __shared__ unsigned short ldsB[128 * 40];   // [px][ic_local], stride 40 u16
    const int t = threadIdx.x;
    const int img = blockIdx.y;
    const int p0 = blockIdx.x * 128;
    const int lane = t & 63, w = t >> 6, l15 = lane & 15, g = lane >> 4;
    constexpr int MF = (OC == 128) ? 4 : 2;
    constexpr int NF = (OC == 128) ? 4 : 2;
    constexpr int WN = (OC == 128) ? 2 : 4;
    const int wm = w / WN, wn = w % WN;
    const int oc0w = wm * MF * 16;
    const int px0w = wn * NF * 16;
    const unsigned short* Wb = Wp + (size_t)(img >> 1) * w_lstride;
    const float* bb = bias + (img >> 1) * b_lstride;
    const float* inb = in + (size_t)img * 262144;

    const int px_l = t & 127;
    const int icg = t >> 7;
    const int pxg = p0 + px_l;
    const int y = pxg >> 5, x = pxg & 31;

    f4acc acc[MF][NF];
    #pragma unroll
    for (int m = 0; m < MF; ++m)
        #pragma unroll
        for (int n = 0; n < NF; ++n) acc[m][n] = (f4acc){0.f, 0.f, 0.f, 0.f};

    for (int tap = 0; tap < 9; ++tap) {
        const int dy = tap / 3 - 1, dx = tap % 3 - 1;
        const int sy = y + dy, sx = x + dx;
        const bool ok = ((unsigned)sy < 32u) && ((unsigned)sx < 32u);
        const int soff = ok ? (sy * 32 + sx) : 0;
        const unsigned short* Wtap = Wb + (size_t)tap * OC * 256;
        for (int ics = 0; ics < 8; ++ics) {
            const int ic0 = ics * 32;
            __syncthreads();
            {
                const float* src = inb + (size_t)(ic0 + icg * 16) * 1024 + soff;
                unsigned uu[8];
                #pragma unroll
                for (int e = 0; e < 8; ++e) {
                    float v0 = src[(size_t)(2 * e) * 1024];
                    float v1 = src[(size_t)(2 * e + 1) * 1024];
                    v0 = ok ? v0 : 0.f;
                    v1 = ok ? v1 : 0.f;
                    uu[e] = (unsigned)f2bf(v0) | ((unsigned)f2bf(v1) << 16);
                }
                *((uint4*)&ldsB[px_l * 40 + icg * 16])     = make_uint4(uu[0], uu[1], uu[2], uu[3]);
                *((uint4*)&ldsB[px_l * 40 + icg * 16 + 8]) = make_uint4(uu[4], uu[5], uu[6], uu[7]);
            }
            __syncthreads();
            bfrag a[MF], bf[NF];
            #pragma unroll
            for (int m = 0; m < MF; ++m)
                a[m] = *((const bfrag*)(Wtap + (size_t)(oc0w + m * 16 + l15) * 256 + ic0 + g * 8));
            #pragma unroll
            for (int n = 0; n < NF; ++n)
                bf[n] = *((const bfrag*)&ldsB[(px0w + n * 16 + l15) * 40 + g * 8]);
            #pragma unroll
            for (int m = 0; m < MF; ++m)
                #pragma unroll
                for (int n = 0; n < NF; ++n)
                    acc[m][n] = __builtin_amdgcn_mfma_f32_16x16x32_bf16(a[m], bf[n], acc[m][n], 0, 0, 0);
        }
    }
    #pragma unroll
    for (int m = 0; m < MF; ++m) {
        #pragma unroll
        for (int n = 0; n < NF; ++n) {
            const int px = p0 + px0w + n * 16 + l15;
            #pragma unroll
            for (int j = 0; j < 4; ++j) {
                const int oc = oc0w + m * 16 + g * 4 + j;
                float val = acc[m][n][j] + bb[oc];
                if (MODE == 0)
                    ((float*)outp)[(size_t)img * 262144 + (size_t)oc * 1024 + px] = val * scale;
                else if (MODE == 1)
                    ((unsigned short*)outp)[((size_t)img * 1024 + px) * OC + oc] = f2bf(val);
                else
                    ((unsigned short*)outp)[(size_t)img * OC * 1024 + (size_t)oc * 1024 + px] = f2bf(val);
            }
        }
    }
}

// ---------------- bilinear (align-corners) resize f(H,W) -> fr(32,32) --------
__global__ __launch_bounds__(256) void resize32(
    const float* __restrict__ f, float* __restrict__ fr, int H, int W)
{
    int g = blockIdx.x * 256 + threadIdx.x;
    int s = g & 1023;
    int c = (g >> 10) & 255;
    int b = g >> 18;
    int oy = s >> 5, ox = s & 31;
    float ty = (float)(oy * (H-1)) / 31.0f;
    float tx = (float)(ox * (W-1)) / 31.0f;
    int y0 = (int)ty; float wy = ty - y0;
    int y1 = min(y0+1, H-1);
    int x0 = (int)tx; float wx = tx - x0;
    int x1 = min(x0+1, W-1);
    const float* p = f + ((size_t)b*256 + c) * (size_t)(H*W);
    float v00 = p[y0*W+x0], v01 = p[y0*W+x1];
    float v10 = p[y1*W+x0], v11 = p[y1*W+x1];
    fr[g] = (v00*(1.f-wx) + v01*wx)*(1.f-wy) + (v10*(1.f-wx) + v11*wx)*wy;
}

// ---------------- MFMA flash attention -> normalized bf16 partials ----------
// grid (16 s-tiles of 64, 15 n, 10 z), block 256 (4 waves).
// part[n][z][c][s] bf16; no atomics.
__global__ __launch_bounds__(256) void attn_mfma(
    const unsigned short* __restrict__ kqT16,  // [10][1024][32]
    const unsigned short* __restrict__ ktT16,  // [15][1024][32]
    const unsigned short* __restrict__ vt16,   // [15][128][1024]
    unsigned short* __restrict__ part)         // [15][10][128][1024] bf16
{
    __shared__ unsigned short P[64 * 136];
    __shared__ float sums[64];
    const int t = threadIdx.x;
    const int w = t >> 6;
    const int lane = t & 63;
    const int l15 = lane & 15;
    const int g = lane >> 4;
    const int s0 = blockIdx.x * 64;
    const int n = blockIdx.y, z = blockIdx.z;

    const bfrag qa = *(const bfrag*)(ktT16 + ((size_t)n*1024 + s0 + w*16 + l15)*32 + g*8);

    f4acc oacc[8];
    #pragma unroll
    for (int ct = 0; ct < 8; ++ct) oacc[ct] = (f4acc){0.f,0.f,0.f,0.f};
    float rs[4] = {0.f, 0.f, 0.f, 0.f};

    const unsigned short* Kbase = kqT16 + (size_t)z * 32768;
    const unsigned short* Vbase = vt16 + (size_t)n * 131072;
    unsigned short* Pw = P + (w * 16) * 136;

    for (int mt = 0; mt < 8; ++mt) {
        const int m0 = mt * 128;
        f4acc sf[8];
        #pragma unroll
        for (int j = 0; j < 8; ++j) {
            bfrag kb = *(const bfrag*)(Kbase + (size_t)(m0 + j*16 + l15)*32 + g*8);
            sf[j] = __builtin_amdgcn_mfma_f32_16x16x32_bf16(qa, kb, (f4acc){0.f,0.f,0.f,0.f}, 0, 0, 0);
        }
        #pragma unroll
        for (int j = 0; j < 8; ++j) {
            #pragma unroll
            for (int r = 0; r < 4; ++r) {
                float e = __expf(sf[j][r]);
                rs[r] += e;
                Pw[(g*4 + r)*136 + j*16 + l15] = f2bf(e);
            }
        }
        // PV: ks outer so pb is loaded once per ks
        #pragma unroll
        for (int ks = 0; ks < 4; ++ks) {
            bfrag pb = *(const bfrag*)(Pw + l15*136 + ks*32 + g*8);
            #pragma unroll
            for (int ct = 0; ct < 8; ++ct) {
                bfrag va = *(const bfrag*)(Vbase + (size_t)(ct*16 + l15)*1024 + m0 + ks*32 + g*8);
                oacc[ct] = __builtin_amdgcn_mfma_f32_16x16x32_bf16(va, pb, oacc[ct], 0, 0, 0);
            }
        }
    }
    #pragma unroll
    for (int d = 1; d < 16; d <<= 1)
        #pragma unroll
        for (int r = 0; r < 4; ++r)
            rs[r] += __shfl_xor(rs[r], d, 64);
    if (l15 == 0) {
        #pragma unroll
        for (int r = 0; r < 4; ++r) sums[w*16 + g*4 + r] = rs[r];
    }
    float inv = 1.f / sums[w*16 + l15];
    unsigned short* pb0 = part + (((size_t)n*10 + z)*128)*1024 + s0 + w*16 + l15;
    #pragma unroll
    for (int ct = 0; ct < 8; ++ct)
        #pragma unroll
        for (int r = 0; r < 4; ++r)
            pb0[(size_t)(ct*16 + g*4 + r)*1024] = f2bf(oacc[ct][r] * inv);
}

// ---------------- fin5 ch128..255 = sum_n part[n] ---------------------------
__global__ __launch_bounds__(256) void reduce_part(
    const unsigned short* __restrict__ part, float* __restrict__ fin5)
{
    int gidx = blockIdx.x * 256 + threadIdx.x;   // 10*128*1024 total
    int s = gidx & 1023;
    int rest = gidx >> 10;
    int c = rest & 127;
    int z = rest >> 7;
    float acc = 0.f;
    #pragma unroll
    for (int n = 0; n < 15; ++n)
        acc += bf2f(part[(((size_t)n*10 + z)*128 + c)*1024 + s]);
    fin5[(size_t)z*262144 + (size_t)(128 + c)*1024 + s] = acc;
}

// ---------------- G = W2' * fin + bias', batched over levels ----------------
__global__ __launch_bounds__(256) void g_kernel(
    const float* __restrict__ fin5, const float* __restrict__ W2t,
    const float* __restrict__ biasP, float* __restrict__ G5)
{
    __shared__ float fv[256];
    const int lev = blockIdx.y;
    int s = blockIdx.x & 1023;
    int b = blockIdx.x >> 10;
    int co = threadIdx.x;
    const float* fin = fin5 + (size_t)lev * 524288;
    fv[co] = fin[((size_t)b*256 + co)*1024 + s];
    __syncthreads();
    float acc = biasP[lev*256 + co];
    const float* W2 = W2t + (size_t)lev * 65536;
    #pragma unroll 8
    for (int ci = 0; ci < 256; ++ci)
        acc += W2[ci*256 + co] * fv[ci];
    G5[(size_t)lev * 524288 + ((size_t)b*256 + co)*1024 + s] = acc;
}

// -------- weight prep: W1 -> bf16 packed [kstep][co][32]; fold BN into W2 ---
__global__ void prep_w(const float* __restrict__ cw, const float* __restrict__ gamma,
                       const float* __restrict__ var, unsigned short* __restrict__ W1s,
                       float* __restrict__ W2t)
{
    int ci = blockIdx.x, co = threadIdx.x;
    W1s[(ci >> 5) * 8192 + co * 32 + (ci & 31)] = f2bf(cw[co*512 + ci]);
    for (int l = 0; l < 5; ++l) {
        float g = gamma[l*256 + ci];
        float rs = rsqrtf(var[l*256 + ci] + 1e-5f);
        W2t[l*65536 + ci*256 + co] = cw[co*512 + 256 + ci] * g * rs;
    }
}

__global__ void prep_bias(const float* __restrict__ cw, const float* __restrict__ cb,
                          const float* __restrict__ gamma, const float* __restrict__ beta,
                          const float* __restrict__ mean, const float* __restrict__ var,
                          float* __restrict__ biasP)
{
    int l = blockIdx.x, co = threadIdx.x;
    float acc = cb[co];
    for (int ci = 0; ci < 256; ++ci) {
        float g = gamma[l*256+ci];
        float rs = rsqrtf(var[l*256+ci] + 1e-5f);
        float k = beta[l*256+ci] - g*rs*mean[l*256+ci];
        acc += cw[co*512 + 256 + ci] * k;
    }
    biasP[l*256 + co] = acc;
}

// ---------------- out = W1*f + bilerp(G)  -- bf16 MFMA GEMM -----------------
__global__ __launch_bounds__(256) void out_mfma(
    const float* __restrict__ f, const unsigned short* __restrict__ W1s,
    const float* __restrict__ G, float* __restrict__ outp, int H, int W)
{
    __shared__ unsigned short ldsB[64 * 40];
    const int HW = H * W;
    const int p0 = blockIdx.x * 64;
    const int b  = blockIdx.y;
    const int t  = threadIdx.x;
    const int lane = t & 63;
    const int wid  = t >> 6;
    const int cw0  = wid * 64;
    const int l15  = lane & 15;
    const int g    = lane >> 4;

    f4acc acc[4][4];
    #pragma unroll
    for (int m = 0; m < 4; ++m)
        #pragma unroll
        for (int n = 0; n < 4; ++n)
            acc[m][n] = (f4acc){0.f, 0.f, 0.f, 0.f};

    const float* fb = f + (size_t)b * 256 * HW;
    const int px_st = t & 63;
    const int cg    = t >> 6;

    for (int s = 0; s < 8; ++s) {
        __syncthreads();
        {
            int p = p0 + px_st;
            bool ok = p < HW;
            const float* src = fb + (size_t)(s * 32 + cg * 8) * HW + p;
            float v[8];
            #pragma unroll
            for (int e = 0; e < 8; ++e) v[e] = ok ? src[(size_t)e * HW] : 0.f;
            unsigned u[4];
            #pragma unroll
            for (int e = 0; e < 4; ++e)
                u[e] = (unsigned)f2bf(v[2*e]) | ((unsigned)f2bf(v[2*e+1]) << 16);
            *((uint4*)&ldsB[px_st * 40 + cg * 8]) = make_uint4(u[0], u[1], u[2], u[3]);
        }
        __syncthreads();
        bfrag a[4], bb[4];
        #pragma unroll
        for (int m = 0; m < 4; ++m)
            a[m] = *((const bfrag*)(W1s + (size_t)s * 8192 + (cw0 + m*16 + l15) * 32 + g * 8));
        #pragma unroll
        for (int n = 0; n < 4; ++n)
            bb[n] = *((const bfrag*)&ldsB[(n*16 + l15) * 40 + g * 8]);
        #pragma unroll
        for (int m = 0; m < 4; ++m)
            #pragma unroll
            for (int n = 0; n < 4; ++n)
                acc[m][n] = __builtin_amdgcn_mfma_f32_16x16x32_bf16(a[m], bb[n], acc[m][n], 0, 0, 0);
    }

    const int r0 = (lane >> 4) * 4;
    #pragma unroll
    for (int n = 0; n < 4; ++n) {
        int px = p0 + n*16 + l15;
        if (px >= HW) continue;
        int yy = px / W;
        int xx = px - yy * W;
        float ty = (float)(yy * 31) / (float)(H - 1);
        float tx = (float)(xx * 31) / (float)(W - 1);
        int y0 = (int)ty; float wy = ty - y0;
        int x0 = (int)tx; float wx = tx - x0;
        int y1 = min(y0 + 1, 31), x1 = min(x0 + 1, 31);
        float w00 = (1.f-wy)*(1.f-wx), w01 = (1.f-wy)*wx;
        float w10 = wy*(1.f-wx),       w11 = wy*wx;
        int i00 = y0*32+x0, i01 = y0*32+x1, i10 = y1*32+x0, i11 = y1*32+x1;
        #pragma unroll
        for (int m = 0; m < 4; ++m) {
            #pragma unroll
            for (int j = 0; j < 4; ++j) {
                int co = cw0 + m*16 + r0 + j;
                const float* gb = G + ((size_t)b*256 + co) * 1024;
                float gv = gb[i00]*w00 + gb[i01]*w01 + gb[i10]*w10 + gb[i11]*w11;
                outp[((size_t)b*256 + co) * HW + px] = acc[m][n][j] + gv;
            }
        }
    }
}

extern "C" void kernel_launch(void* const* d_in, const int* in_sizes, int n_in,
                              void* d_out, int out_size, void* d_ws, size_t ws_size,
                              hipStream_t stream)
{
    const float* f[5]; for (int i = 0; i < 5; ++i) f[i] = (const float*)d_in[i];
    const float* att   = (const float*)d_in[5];
    const float* ktw   = (const float*)d_in[6];
    const float* ktb   = (const float*)d_in[7];
    const float* vtw   = (const float*)d_in[8];
    const float* vtb   = (const float*)d_in[9];
    const float* kqw   = (const float*)d_in[10];
    const float* kqbb  = (const float*)d_in[11];
    const float* vqw   = (const float*)d_in[12];
    const float* vqb   = (const float*)d_in[13];
    const float* gamma = (const float*)d_in[14];
    const float* beta  = (const float*)d_in[15];
    const float* mean  = (const float*)d_in[16];
    const float* var   = (const float*)d_in[17];
    const float* cw    = (const float*)d_in[18];
    const float* cb    = (const float*)d_in[19];
    float* outp = (float*)d_out;

    unsigned short* ktT16 = (unsigned short*)d_ws;      // 491520
    unsigned short* kqT16 = ktT16 + 491520;             // 327680
    unsigned short* vt16  = kqT16 + 327680;             // 1966080
    unsigned short* wpkt  = vt16 + 1966080;             // 73728
    unsigned short* wpvt  = wpkt + 73728;               // 294912
    unsigned short* wpkq  = wpvt + 294912;              // 368640
    unsigned short* wpvq  = wpkq + 368640;              // 1474560
    unsigned short* W1s   = wpvq + 1474560;             // 65536
    float* W2t   = (float*)(W1s + 65536);               // 327680 f
    float* biasP = W2t + 327680;                        // 1280
    float* fr5   = biasP + 1280;                        // 2621440
    float* fin5  = fr5 + 2621440;                       // 2621440
    float* G5    = fin5 + 2621440;                      // 2621440
    unsigned short* partb = (unsigned short*)(G5 + 2621440);  // 19660800 u16

    prep_w<<<256, 256, 0, stream>>>(cw, gamma, var, W1s, W2t);
    prep_bias<<<5, 256, 0, stream>>>(cw, cb, gamma, beta, mean, var, biasP);
    pack_w<<<dim3(288, 1),  256, 0, stream>>>(ktw, wpkt, 32);
    pack_w<<<dim3(1152, 1), 256, 0, stream>>>(vtw, wpvt, 128);
    pack_w<<<dim3(288, 5),  256, 0, stream>>>(kqw, wpkq, 32);
    pack_w<<<dim3(1152, 5), 256, 0, stream>>>(vqw, wpvq, 128);

    convgemm<32, 1><<<dim3(8, 15), 256, 0, stream>>>(att, wpkt, 0, ktb, 0, ktT16, 1.f);
    convgemm<128, 2><<<dim3(8, 15), 256, 0, stream>>>(att, wpvt, 0, vtb, 0, vt16, 1.f);

    const int Hs[5] = {200,100,50,25,13};
    const int Ws[5] = {336,168,84,42,21};
    for (int l = 0; l < 5; ++l)
        resize32<<<2048, 256, 0, stream>>>(f[l], fr5 + (size_t)l*524288, Hs[l], Ws[l]);

    convgemm<32, 1><<<dim3(8, 10), 256, 0, stream>>>(fr5, wpkq, 73728, kqbb, 32, kqT16, 1.f);
    convgemm<128, 0><<<dim3(8, 10), 256, 0, stream>>>(fr5, wpvq, 294912, vqb, 128, fin5, 15.f);

    attn_mfma<<<dim3(16, 15, 10), 256, 0, stream>>>(kqT16, ktT16, vt16, partb);
    reduce_part<<<5120, 256, 0, stream>>>(partb, fin5);
    g_kernel<<<dim3(2048, 5), 256, 0, stream>>>(fin5, W2t, biasP, G5);

    size_t ooff = 0;
    for (int l = 0; l < 5; ++l) {
        int H = Hs[l], W = Ws[l], HW = H*W;
        out_mfma<<<dim3((HW+63)/64, 2), 256, 0, stream>>>(f[l], W1s, G5 + (size_t)l*524288, outp + ooff, H, W);
        ooff += (size_t)2*256*HW;
    }
}

// Round 7
// 904.867 us; speedup vs baseline: 8.7684x; 1.1890x over previous
//
#include <hip/hip_runtime.h>

typedef __attribute__((ext_vector_type(8))) short bfrag;
typedef __attribute__((ext_vector_type(4))) float f4acc;

__device__ inline unsigned short f2bf(float x) {
    unsigned u = __float_as_uint(x);
    unsigned r = (u + 0x7FFF + ((u >> 16) & 1)) >> 16;
    return (unsigned short)r;
}
__device__ inline float bf2f(unsigned short h) {
    unsigned u = ((unsigned)h) << 16;
    return __uint_as_float(u);
}

// -------- pack conv weights: w[lev][OC][256][3][3] -> Wp[lev][9][OC][256] bf16
__global__ __launch_bounds__(256) void pack_w(
    const float* __restrict__ src, unsigned short* __restrict__ dst, int OC)
{
    const int lev = blockIdx.y;
    const int tot = OC * 2304;
    int g = blockIdx.x * 256 + threadIdx.x;
    if (g >= tot) return;
    int ic = g & 255;
    int rest = g >> 8;
    int oc = rest % OC;
    int tap = rest / OC;
    dst[(size_t)lev * tot + g] = f2bf(src[(size_t)lev * tot + ((size_t)oc * 256 + ic) * 9 + tap]);
}

// -------- conv3x3 as 9-tap implicit GEMM, bf16 MFMA ------------------------
// MODE 0: f32 out[img][OC][1024] (stride 262144), *scale
// MODE 1: bf16 out[img][1024][OC] (transposed, row-contiguous; attn K/Q operand)
// MODE 2: bf16 V in MFMA-fragment order: chunk=(oc>>4)*32+(px>>5) of 512,
//         lane=(oc&15)|(((px>>3)&3)<<4), elem=px&7
template<int OC, int MODE>
__global__ __launch_bounds__(256) void convgemm(
    const float* __restrict__ in, const unsigned short* __restrict__ Wp,
    int w_lstride, const float* __restrict__ bias, int b_lstride,
    void* __restrict__ outp, float scale)
{
    __shared__ unsigned short ldsB[128 * 40];   // [px][ic_local], stride 40 u16
    const int t = threadIdx.x;
    const int img = blockIdx.y;
    const int p0 = blockIdx.x * 128;
    const int lane = t & 63, w = t >> 6, l15 = lane & 15, g = lane >> 4;
    constexpr int MF = (OC == 128) ? 4 : 2;
    constexpr int NF = (OC == 128) ? 4 : 2;
    constexpr int WN = (OC == 128) ? 2 : 4;
    const int wm = w / WN, wn = w % WN;
    const int oc0w = wm * MF * 16;
    const int px0w = wn * NF * 16;
    const unsigned short* Wb = Wp + (size_t)(img >> 1) * w_lstride;
    const float* bb = bias + (img >> 1) * b_lstride;
    const float* inb = in + (size_t)img * 262144;

    const int px_l = t & 127;
    const int icg = t >> 7;
    const int pxg = p0 + px_l;
    const int y = pxg >> 5, x = pxg & 31;

    f4acc acc[MF][NF];
    #pragma unroll
    for (int m = 0; m < MF; ++m)
        #pragma unroll
        for (int n = 0; n < NF; ++n) acc[m][n] = (f4acc){0.f, 0.f, 0.f, 0.f};

    for (int tap = 0; tap < 9; ++tap) {
        const int dy = tap / 3 - 1, dx = tap % 3 - 1;
        const int sy = y + dy, sx = x + dx;
        const bool ok = ((unsigned)sy < 32u) && ((unsigned)sx < 32u);
        const int soff = ok ? (sy * 32 + sx) : 0;
        const unsigned short* Wtap = Wb + (size_t)tap * OC * 256;
        for (int ics = 0; ics < 8; ++ics) {
            const int ic0 = ics * 32;
            __syncthreads();
            {
                const float* src = inb + (size_t)(ic0 + icg * 16) * 1024 + soff;
                unsigned uu[8];
                #pragma unroll
                for (int e = 0; e < 8; ++e) {
                    float v0 = src[(size_t)(2 * e) * 1024];
                    float v1 = src[(size_t)(2 * e + 1) * 1024];
                    v0 = ok ? v0 : 0.f;
                    v1 = ok ? v1 : 0.f;
                    uu[e] = (unsigned)f2bf(v0) | ((unsigned)f2bf(v1) << 16);
                }
                *((uint4*)&ldsB[px_l * 40 + icg * 16])     = make_uint4(uu[0], uu[1], uu[2], uu[3]);
                *((uint4*)&ldsB[px_l * 40 + icg * 16 + 8]) = make_uint4(uu[4], uu[5], uu[6], uu[7]);
            }
            __syncthreads();
            bfrag a[MF], bf[NF];
            #pragma unroll
            for (int m = 0; m < MF; ++m)
                a[m] = *((const bfrag*)(Wtap + (size_t)(oc0w + m * 16 + l15) * 256 + ic0 + g * 8));
            #pragma unroll
            for (int n = 0; n < NF; ++n)
                bf[n] = *((const bfrag*)&ldsB[(px0w + n * 16 + l15) * 40 + g * 8]);
            #pragma unroll
            for (int m = 0; m < MF; ++m)
                #pragma unroll
                for (int n = 0; n < NF; ++n)
                    acc[m][n] = __builtin_amdgcn_mfma_f32_16x16x32_bf16(a[m], bf[n], acc[m][n], 0, 0, 0);
        }
    }
    #pragma unroll
    for (int m = 0; m < MF; ++m) {
        #pragma unroll
        for (int n = 0; n < NF; ++n) {
            const int px = p0 + px0w + n * 16 + l15;
            #pragma unroll
            for (int j = 0; j < 4; ++j) {
                const int oc = oc0w + m * 16 + g * 4 + j;
                float val = acc[m][n][j] + bb[oc];
                if (MODE == 0)
                    ((float*)outp)[(size_t)img * 262144 + (size_t)oc * 1024 + px] = val * scale;
                else if (MODE == 1)
                    ((unsigned short*)outp)[((size_t)img * 1024 + px) * OC + oc] = f2bf(val);
                else {
                    // V fragment order
                    int chunk = ((oc >> 4) << 5) + (px >> 5);
                    int lidx = (oc & 15) | (((px >> 3) & 3) << 4);
                    ((unsigned short*)outp)[(size_t)img * 131072 + ((size_t)chunk << 9) + lidx * 8 + (px & 7)] = f2bf(val);
                }
            }
        }
    }
}

// ---------------- bilinear (align-corners) resize f(H,W) -> fr(32,32) --------
__global__ __launch_bounds__(256) void resize32(
    const float* __restrict__ f, float* __restrict__ fr, int H, int W)
{
    int g = blockIdx.x * 256 + threadIdx.x;
    int s = g & 1023;
    int c = (g >> 10) & 255;
    int b = g >> 18;
    int oy = s >> 5, ox = s & 31;
    float ty = (float)(oy * (H-1)) / 31.0f;
    float tx = (float)(ox * (W-1)) / 31.0f;
    int y0 = (int)ty; float wy = ty - y0;
    int y1 = min(y0+1, H-1);
    int x0 = (int)tx; float wx = tx - x0;
    int x1 = min(x0+1, W-1);
    const float* p = f + ((size_t)b*256 + c) * (size_t)(H*W);
    float v00 = p[y0*W+x0], v01 = p[y0*W+x1];
    float v10 = p[y1*W+x0], v11 = p[y1*W+x1];
    fr[g] = (v00*(1.f-wx) + v01*wx)*(1.f-wy) + (v10*(1.f-wx) + v11*wx)*wy;
}

// ---------------- MFMA flash attention -> normalized bf16 partials ----------
// grid (16 s-tiles of 64, 15 n, 10 z), block 256 (4 waves).
__global__ __launch_bounds__(256) void attn_mfma(
    const unsigned short* __restrict__ kqT16,  // [10][1024][32]
    const unsigned short* __restrict__ ktT16,  // [15][1024][32]
    const unsigned short* __restrict__ vt16,   // [15] frag-order chunks
    unsigned short* __restrict__ part)         // [15][10][128][1024] bf16
{
    __shared__ unsigned short P[64 * 136];
    __shared__ float sums[64];
    const int t = threadIdx.x;
    const int w = t >> 6;
    const int lane = t & 63;
    const int l15 = lane & 15;
    const int g = lane >> 4;
    const int s0 = blockIdx.x * 64;
    const int n = blockIdx.y, z = blockIdx.z;

    const bfrag qa = *(const bfrag*)(ktT16 + ((size_t)n*1024 + s0 + w*16 + l15)*32 + g*8);

    f4acc oacc[8];
    #pragma unroll
    for (int ct = 0; ct < 8; ++ct) oacc[ct] = (f4acc){0.f,0.f,0.f,0.f};
    float rs[4] = {0.f, 0.f, 0.f, 0.f};

    const unsigned short* Kbase = kqT16 + (size_t)z * 32768;
    const unsigned short* Vbase = vt16 + (size_t)n * 131072;
    unsigned short* Pw = P + (w * 16) * 136;

    for (int mt = 0; mt < 8; ++mt) {
        const int m0 = mt * 128;
        f4acc sf[8];
        #pragma unroll
        for (int j = 0; j < 8; ++j) {
            bfrag kb = *(const bfrag*)(Kbase + (size_t)(m0 + j*16 + l15)*32 + g*8);
            sf[j] = __builtin_amdgcn_mfma_f32_16x16x32_bf16(qa, kb, (f4acc){0.f,0.f,0.f,0.f}, 0, 0, 0);
        }
        #pragma unroll
        for (int j = 0; j < 8; ++j) {
            #pragma unroll
            for (int r = 0; r < 4; ++r) {
                float e = __expf(sf[j][r]);
                rs[r] += e;
                Pw[(g*4 + r)*136 + j*16 + l15] = f2bf(e);
            }
        }
        // PV: V fragment chunks are contiguous 1KB wave loads
        __builtin_amdgcn_s_setprio(1);
        #pragma unroll
        for (int ks = 0; ks < 4; ++ks) {
            bfrag pb = *(const bfrag*)(Pw + l15*136 + ks*32 + g*8);
            #pragma unroll
            for (int ct = 0; ct < 8; ++ct) {
                bfrag va = *(const bfrag*)(Vbase + (((size_t)(ct*32 + mt*4 + ks)) << 9) + lane*8);
                oacc[ct] = __builtin_amdgcn_mfma_f32_16x16x32_bf16(va, pb, oacc[ct], 0, 0, 0);
            }
        }
        __builtin_amdgcn_s_setprio(0);
    }
    #pragma unroll
    for (int d = 1; d < 16; d <<= 1)
        #pragma unroll
        for (int r = 0; r < 4; ++r)
            rs[r] += __shfl_xor(rs[r], d, 64);
    if (l15 == 0) {
        #pragma unroll
        for (int r = 0; r < 4; ++r) sums[w*16 + g*4 + r] = rs[r];
    }
    float inv = 1.f / sums[w*16 + l15];
    unsigned short* pb0 = part + (((size_t)n*10 + z)*128)*1024 + s0 + w*16 + l15;
    #pragma unroll
    for (int ct = 0; ct < 8; ++ct)
        #pragma unroll
        for (int r = 0; r < 4; ++r)
            pb0[(size_t)(ct*16 + g*4 + r)*1024] = f2bf(oacc[ct][r] * inv);
}

// ---------------- fin5 ch128..255 = sum_n part[n] ---------------------------
__global__ __launch_bounds__(256) void reduce_part(
    const unsigned short* __restrict__ part, float* __restrict__ fin5)
{
    int gidx = blockIdx.x * 256 + threadIdx.x;   // 10*128*1024 total
    int s = gidx & 1023;
    int rest = gidx >> 10;
    int c = rest & 127;
    int z = rest >> 7;
    float acc = 0.f;
    #pragma unroll
    for (int n = 0; n < 15; ++n)
        acc += bf2f(part[(((size_t)n*10 + z)*128 + c)*1024 + s]);
    fin5[(size_t)z*262144 + (size_t)(128 + c)*1024 + s] = acc;
}

// ---------------- G = W2' * fin + bias', batched over levels ----------------
__global__ __launch_bounds__(256) void g_kernel(
    const float* __restrict__ fin5, const float* __restrict__ W2t,
    const float* __restrict__ biasP, float* __restrict__ G5)
{
    __shared__ float fv[256];
    const int lev = blockIdx.y;
    int s = blockIdx.x & 1023;
    int b = blockIdx.x >> 10;
    int co = threadIdx.x;
    const float* fin = fin5 + (size_t)lev * 524288;
    fv[co] = fin[((size_t)b*256 + co)*1024 + s];
    __syncthreads();
    float acc = biasP[lev*256 + co];
    const float* W2 = W2t + (size_t)lev * 65536;
    #pragma unroll 8
    for (int ci = 0; ci < 256; ++ci)
        acc += W2[ci*256 + co] * fv[ci];
    G5[(size_t)lev * 524288 + ((size_t)b*256 + co)*1024 + s] = acc;
}

// -------- weight prep: W1 -> bf16 packed [kstep][co][32]; fold BN into W2 ---
__global__ void prep_w(const float* __restrict__ cw, const float* __restrict__ gamma,
                       const float* __restrict__ var, unsigned short* __restrict__ W1s,
                       float* __restrict__ W2t)
{
    int ci = blockIdx.x, co = threadIdx.x;
    W1s[(ci >> 5) * 8192 + co * 32 + (ci & 31)] = f2bf(cw[co*512 + ci]);
    for (int l = 0; l < 5; ++l) {
        float g = gamma[l*256 + ci];
        float rs = rsqrtf(var[l*256 + ci] + 1e-5f);
        W2t[l*65536 + ci*256 + co] = cw[co*512 + 256 + ci] * g * rs;
    }
}

__global__ void prep_bias(const float* __restrict__ cw, const float* __restrict__ cb,
                          const float* __restrict__ gamma, const float* __restrict__ beta,
                          const float* __restrict__ mean, const float* __restrict__ var,
                          float* __restrict__ biasP)
{
    int l = blockIdx.x, co = threadIdx.x;
    float acc = cb[co];
    for (int ci = 0; ci < 256; ++ci) {
        float g = gamma[l*256+ci];
        float rs = rsqrtf(var[l*256+ci] + 1e-5f);
        float k = beta[l*256+ci] - g*rs*mean[l*256+ci];
        acc += cw[co*512 + 256 + ci] * k;
    }
    biasP[l*256 + co] = acc;
}

// ---------------- out = W1*f + bilerp(G)  -- bf16 MFMA GEMM -----------------
__global__ __launch_bounds__(256) void out_mfma(
    const float* __restrict__ f, const unsigned short* __restrict__ W1s,
    const float* __restrict__ G, float* __restrict__ outp, int H, int W)
{
    __shared__ unsigned short ldsB[64 * 40];
    const int HW = H * W;
    const int p0 = blockIdx.x * 64;
    const int b  = blockIdx.y;
    const int t  = threadIdx.x;
    const int lane = t & 63;
    const int wid  = t >> 6;
    const int cw0  = wid * 64;
    const int l15  = lane & 15;
    const int g    = lane >> 4;

    f4acc acc[4][4];
    #pragma unroll
    for (int m = 0; m < 4; ++m)
        #pragma unroll
        for (int n = 0; n < 4; ++n)
            acc[m][n] = (f4acc){0.f, 0.f, 0.f, 0.f};

    const float* fb = f + (size_t)b * 256 * HW;
    const int px_st = t & 63;
    const int cg    = t >> 6;

    for (int s = 0; s < 8; ++s) {
        __syncthreads();
        {
            int p = p0 + px_st;
            bool ok = p < HW;
            const float* src = fb + (size_t)(s * 32 + cg * 8) * HW + p;
            float v[8];
            #pragma unroll
            for (int e = 0; e < 8; ++e) v[e] = ok ? src[(size_t)e * HW] : 0.f;
            unsigned u[4];
            #pragma unroll
            for (int e = 0; e < 4; ++e)
                u[e] = (unsigned)f2bf(v[2*e]) | ((unsigned)f2bf(v[2*e+1]) << 16);
            *((uint4*)&ldsB[px_st * 40 + cg * 8]) = make_uint4(u[0], u[1], u[2], u[3]);
        }
        __syncthreads();
        bfrag a[4], bb[4];
        #pragma unroll
        for (int m = 0; m < 4; ++m)
            a[m] = *((const bfrag*)(W1s + (size_t)s * 8192 + (cw0 + m*16 + l15) * 32 + g * 8));
        #pragma unroll
        for (int n = 0; n < 4; ++n)
            bb[n] = *((const bfrag*)&ldsB[(n*16 + l15) * 40 + g * 8]);
        #pragma unroll
        for (int m = 0; m < 4; ++m)
            #pragma unroll
            for (int n = 0; n < 4; ++n)
                acc[m][n] = __builtin_amdgcn_mfma_f32_16x16x32_bf16(a[m], bb[n], acc[m][n], 0, 0, 0);
    }

    const int r0 = (lane >> 4) * 4;
    #pragma unroll
    for (int n = 0; n < 4; ++n) {
        int px = p0 + n*16 + l15;
        if (px >= HW) continue;
        int yy = px / W;
        int xx = px - yy * W;
        float ty = (float)(yy * 31) / (float)(H - 1);
        float tx = (float)(xx * 31) / (float)(W - 1);
        int y0 = (int)ty; float wy = ty - y0;
        int x0 = (int)tx; float wx = tx - x0;
        int y1 = min(y0 + 1, 31), x1 = min(x0 + 1, 31);
        float w00 = (1.f-wy)*(1.f-wx), w01 = (1.f-wy)*wx;
        float w10 = wy*(1.f-wx),       w11 = wy*wx;
        int i00 = y0*32+x0, i01 = y0*32+x1, i10 = y1*32+x0, i11 = y1*32+x1;
        #pragma unroll
        for (int m = 0; m < 4; ++m) {
            #pragma unroll
            for (int j = 0; j < 4; ++j) {
                int co = cw0 + m*16 + r0 + j;
                const float* gb = G + ((size_t)b*256 + co) * 1024;
                float gv = gb[i00]*w00 + gb[i01]*w01 + gb[i10]*w10 + gb[i11]*w11;
                outp[((size_t)b*256 + co) * HW + px] = acc[m][n][j] + gv;
            }
        }
    }
}

extern "C" void kernel_launch(void* const* d_in, const int* in_sizes, int n_in,
                              void* d_out, int out_size, void* d_ws, size_t ws_size,
                              hipStream_t stream)
{
    const float* f[5]; for (int i = 0; i < 5; ++i) f[i] = (const float*)d_in[i];
    const float* att   = (const float*)d_in[5];
    const float* ktw   = (const float*)d_in[6];
    const float* ktb   = (const float*)d_in[7];
    const float* vtw   = (const float*)d_in[8];
    const float* vtb   = (const float*)d_in[9];
    const float* kqw   = (const float*)d_in[10];
    const float* kqbb  = (const float*)d_in[11];
    const float* vqw   = (const float*)d_in[12];
    const float* vqb   = (const float*)d_in[13];
    const float* gamma = (const float*)d_in[14];
    const float* beta  = (const float*)d_in[15];
    const float* mean  = (const float*)d_in[16];
    const float* var   = (const float*)d_in[17];
    const float* cw    = (const float*)d_in[18];
    const float* cb    = (const float*)d_in[19];
    float* outp = (float*)d_out;

    unsigned short* ktT16 = (unsigned short*)d_ws;      // 491520
    unsigned short* kqT16 = ktT16 + 491520;             // 327680
    unsigned short* vt16  = kqT16 + 327680;             // 1966080
    unsigned short* wpkt  = vt16 + 1966080;             // 73728
    unsigned short* wpvt  = wpkt + 73728;               // 294912
    unsigned short* wpkq  = wpvt + 294912;              // 368640
    unsigned short* wpvq  = wpkq + 368640;              // 1474560
    unsigned short* W1s   = wpvq + 1474560;             // 65536
    float* W2t   = (float*)(W1s + 65536);               // 327680 f
    float* biasP = W2t + 327680;                        // 1280
    float* fr5   = biasP + 1280;                        // 2621440
    float* fin5  = fr5 + 2621440;                       // 2621440
    float* G5    = fin5 + 2621440;                      // 2621440
    unsigned short* partb = (unsigned short*)(G5 + 2621440);  // 19660800 u16

    prep_w<<<256, 256, 0, stream>>>(cw, gamma, var, W1s, W2t);
    prep_bias<<<5, 256, 0, stream>>>(cw, cb, gamma, beta, mean, var, biasP);
    pack_w<<<dim3(288, 1),  256, 0, stream>>>(ktw, wpkt, 32);
    pack_w<<<dim3(1152, 1), 256, 0, stream>>>(vtw, wpvt, 128);
    pack_w<<<dim3(288, 5),  256, 0, stream>>>(kqw, wpkq, 32);
    pack_w<<<dim3(1152, 5), 256, 0, stream>>>(vqw, wpvq, 128);

    convgemm<32, 1><<<dim3(8, 15), 256, 0, stream>>>(att, wpkt, 0, ktb, 0, ktT16, 1.f);
    convgemm<128, 2><<<dim3(8, 15), 256, 0, stream>>>(att, wpvt, 0, vtb, 0, vt16, 1.f);

    const int Hs[5] = {200,100,50,25,13};
    const int Ws[5] = {336,168,84,42,21};
    for (int l = 0; l < 5; ++l)
        resize32<<<2048, 256, 0, stream>>>(f[l], fr5 + (size_t)l*524288, Hs[l], Ws[l]);

    convgemm<32, 1><<<dim3(8, 10), 256, 0, stream>>>(fr5, wpkq, 73728, kqbb, 32, kqT16, 1.f);
    convgemm<128, 0><<<dim3(8, 10), 256, 0, stream>>>(fr5, wpvq, 294912, vqb, 128, fin5, 15.f);

    attn_mfma<<<dim3(16, 15, 10), 256, 0, stream>>>(kqT16, ktT16, vt16, partb);
    reduce_part<<<5120, 256, 0, stream>>>(partb, fin5);
    g_kernel<<<dim3(2048, 5), 256, 0, stream>>>(fin5, W2t, biasP, G5);

    size_t ooff = 0;
    for (int l = 0; l < 5; ++l) {
        int H = Hs[l], W = Ws[l], HW = H*W;
        out_mfma<<<dim3((HW+63)/64, 2), 256, 0, stream>>>(f[l], W1s, G5 + (size_t)l*524288, outp + ooff, H, W);
        ooff += (size_t)2*256*HW;
    }
}

// Round 8
// 751.146 us; speedup vs baseline: 10.5628x; 1.2046x over previous
//
#include <hip/hip_runtime.h>

typedef __attribute__((ext_vector_type(8))) short bfrag;
typedef __attribute__((ext_vector_type(4))) float f4acc;

__device__ inline unsigned short f2bf(float x) {
    unsigned u = __float_as_uint(x);
    unsigned r = (u + 0x7FFF + ((u >> 16) & 1)) >> 16;
    return (unsigned short)r;
}
__device__ inline float bf2f(unsigned short h) {
    unsigned u = ((unsigned)h) << 16;
    return __uint_as_float(u);
}

// -------- pack conv weights: w[lev][OC][256][3][3] -> Wp[lev][9][OC][256] bf16
__global__ __launch_bounds__(256) void pack_w(
    const float* __restrict__ src, unsigned short* __restrict__ dst, int OC)
{
    const int lev = blockIdx.y;
    const int tot = OC * 2304;
    int g = blockIdx.x * 256 + threadIdx.x;
    if (g >= tot) return;
    int ic = g & 255;
    int rest = g >> 8;
    int oc = rest % OC;
    int tap = rest / OC;
    dst[(size_t)lev * tot + g] = f2bf(src[(size_t)lev * tot + ((size_t)oc * 256 + ic) * 9 + tap]);
}

// -------- conv3x3 as 9-tap implicit GEMM, bf16 MFMA ------------------------
// MODE 1: bf16 out[img][1024][OC] (transposed; attn K/Q operands)
// MODE 2: bf16 V in MFMA-fragment order (chunks of 512 u16)
// MODE 3: bf16 out[img][1024][256] cols 0..OC-1 (transposed, stride 256), *scale
template<int OC, int MODE>
__global__ __launch_bounds__(256) void convgemm(
    const float* __restrict__ in, const unsigned short* __restrict__ Wp,
    int w_lstride, const float* __restrict__ bias, int b_lstride,
    void* __restrict__ outp, float scale)
{
    __shared__ unsigned short ldsB[128 * 40];   // [px][ic_local], stride 40 u16
    const int t = threadIdx.x;
    const int img = blockIdx.y;
    const int p0 = blockIdx.x * 128;
    const int lane = t & 63, w = t >> 6, l15 = lane & 15, g = lane >> 4;
    constexpr int MF = (OC == 128) ? 4 : 2;
    constexpr int NF = (OC == 128) ? 4 : 2;
    constexpr int WN = (OC == 128) ? 2 : 4;
    const int wm = w / WN, wn = w % WN;
    const int oc0w = wm * MF * 16;
    const int px0w = wn * NF * 16;
    const unsigned short* Wb = Wp + (size_t)(img >> 1) * w_lstride;
    const float* bb = bias + (img >> 1) * b_lstride;
    const float* inb = in + (size_t)img * 262144;

    const int px_l = t & 127;
    const int icg = t >> 7;
    const int pxg = p0 + px_l;
    const int y = pxg >> 5, x = pxg & 31;

    f4acc acc[MF][NF];
    #pragma unroll
    for (int m = 0; m < MF; ++m)
        #pragma unroll
        for (int n = 0; n < NF; ++n) acc[m][n] = (f4acc){0.f, 0.f, 0.f, 0.f};

    for (int tap = 0; tap < 9; ++tap) {
        const int dy = tap / 3 - 1, dx = tap % 3 - 1;
        const int sy = y + dy, sx = x + dx;
        const bool ok = ((unsigned)sy < 32u) && ((unsigned)sx < 32u);
        const int soff = ok ? (sy * 32 + sx) : 0;
        const unsigned short* Wtap = Wb + (size_t)tap * OC * 256;
        for (int ics = 0; ics < 8; ++ics) {
            const int ic0 = ics * 32;
            __syncthreads();
            {
                const float* src = inb + (size_t)(ic0 + icg * 16) * 1024 + soff;
                unsigned uu[8];
                #pragma unroll
                for (int e = 0; e < 8; ++e) {
                    float v0 = src[(size_t)(2 * e) * 1024];
                    float v1 = src[(size_t)(2 * e + 1) * 1024];
                    v0 = ok ? v0 : 0.f;
                    v1 = ok ? v1 : 0.f;
                    uu[e] = (unsigned)f2bf(v0) | ((unsigned)f2bf(v1) << 16);
                }
                *((uint4*)&ldsB[px_l * 40 + icg * 16])     = make_uint4(uu[0], uu[1], uu[2], uu[3]);
                *((uint4*)&ldsB[px_l * 40 + icg * 16 + 8]) = make_uint4(uu[4], uu[5], uu[6], uu[7]);
            }
            __syncthreads();
            bfrag a[MF], bf[NF];
            #pragma unroll
            for (int m = 0; m < MF; ++m)
                a[m] = *((const bfrag*)(Wtap + (size_t)(oc0w + m * 16 + l15) * 256 + ic0 + g * 8));
            #pragma unroll
            for (int n = 0; n < NF; ++n)
                bf[n] = *((const bfrag*)&ldsB[(px0w + n * 16 + l15) * 40 + g * 8]);
            #pragma unroll
            for (int m = 0; m < MF; ++m)
                #pragma unroll
                for (int n = 0; n < NF; ++n)
                    acc[m][n] = __builtin_amdgcn_mfma_f32_16x16x32_bf16(a[m], bf[n], acc[m][n], 0, 0, 0);
        }
    }
    #pragma unroll
    for (int m = 0; m < MF; ++m) {
        #pragma unroll
        for (int n = 0; n < NF; ++n) {
            const int px = p0 + px0w + n * 16 + l15;
            #pragma unroll
            for (int j = 0; j < 4; ++j) {
                const int oc = oc0w + m * 16 + g * 4 + j;
                float val = acc[m][n][j] + bb[oc];
                if (MODE == 1)
                    ((unsigned short*)outp)[((size_t)img * 1024 + px) * OC + oc] = f2bf(val);
                else if (MODE == 2) {
                    int chunk = ((oc >> 4) << 5) + (px >> 5);
                    int lidx = (oc & 15) | (((px >> 3) & 3) << 4);
                    ((unsigned short*)outp)[(size_t)img * 131072 + ((size_t)chunk << 9) + lidx * 8 + (px & 7)] = f2bf(val);
                } else {
                    ((unsigned short*)outp)[((size_t)img * 1024 + px) * 256 + oc] = f2bf(val * scale);
                }
            }
        }
    }
}

// ---------------- bilinear (align-corners) resize f(H,W) -> fr(32,32) --------
__global__ __launch_bounds__(256) void resize32(
    const float* __restrict__ f, float* __restrict__ fr, int H, int W)
{
    int g = blockIdx.x * 256 + threadIdx.x;
    int s = g & 1023;
    int c = (g >> 10) & 255;
    int b = g >> 18;
    int oy = s >> 5, ox = s & 31;
    float ty = (float)(oy * (H-1)) / 31.0f;
    float tx = (float)(ox * (W-1)) / 31.0f;
    int y0 = (int)ty; float wy = ty - y0;
    int y1 = min(y0+1, H-1);
    int x0 = (int)tx; float wx = tx - x0;
    int x1 = min(x0+1, W-1);
    const float* p = f + ((size_t)b*256 + c) * (size_t)(H*W);
    float v00 = p[y0*W+x0], v01 = p[y0*W+x1];
    float v10 = p[y1*W+x0], v11 = p[y1*W+x1];
    fr[g] = (v00*(1.f-wx) + v01*wx)*(1.f-wy) + (v10*(1.f-wx) + v11*wx)*wy;
}

// ---------------- MFMA flash attention, 1-wave blocks, 2 s-subtiles ---------
// grid (32 s-tiles of 32, 15 n, 10 z), block 64.
__global__ __launch_bounds__(64) void attn_mfma(
    const unsigned short* __restrict__ kqT16,  // [10][1024][32]
    const unsigned short* __restrict__ ktT16,  // [15][1024][32]
    const unsigned short* __restrict__ vt16,   // [15] frag-order chunks
    unsigned short* __restrict__ part)         // [15][10][128][1024] bf16
{
    __shared__ unsigned short P[32 * 136];
    __shared__ float sums[32];
    const int lane = threadIdx.x;
    const int l15 = lane & 15;
    const int g = lane >> 4;
    const int s0 = blockIdx.x * 32;
    const int n = blockIdx.y, z = blockIdx.z;

    const bfrag qa0 = *(const bfrag*)(ktT16 + ((size_t)n*1024 + s0 + l15)*32 + g*8);
    const bfrag qa1 = *(const bfrag*)(ktT16 + ((size_t)n*1024 + s0 + 16 + l15)*32 + g*8);

    f4acc oacc0[8], oacc1[8];
    #pragma unroll
    for (int ct = 0; ct < 8; ++ct) {
        oacc0[ct] = (f4acc){0.f,0.f,0.f,0.f};
        oacc1[ct] = (f4acc){0.f,0.f,0.f,0.f};
    }
    float rs0[4] = {0.f,0.f,0.f,0.f}, rs1[4] = {0.f,0.f,0.f,0.f};

    const unsigned short* Kbase = kqT16 + (size_t)z * 32768;
    const unsigned short* Vbase = vt16 + (size_t)n * 131072;

    for (int mt = 0; mt < 8; ++mt) {
        const int m0 = mt * 128;
        #pragma unroll
        for (int j = 0; j < 8; ++j) {
            bfrag kb = *(const bfrag*)(Kbase + (size_t)(m0 + j*16 + l15)*32 + g*8);
            f4acc sf0 = __builtin_amdgcn_mfma_f32_16x16x32_bf16(qa0, kb, (f4acc){0.f,0.f,0.f,0.f}, 0, 0, 0);
            f4acc sf1 = __builtin_amdgcn_mfma_f32_16x16x32_bf16(qa1, kb, (f4acc){0.f,0.f,0.f,0.f}, 0, 0, 0);
            #pragma unroll
            for (int r = 0; r < 4; ++r) {
                float e0 = __expf(sf0[r]); rs0[r] += e0;
                P[(g*4 + r)*136 + j*16 + l15] = f2bf(e0);
                float e1 = __expf(sf1[r]); rs1[r] += e1;
                P[(16 + g*4 + r)*136 + j*16 + l15] = f2bf(e1);
            }
        }
        __builtin_amdgcn_s_setprio(1);
        #pragma unroll
        for (int ks = 0; ks < 4; ++ks) {
            bfrag pb0 = *(const bfrag*)(P + l15*136 + ks*32 + g*8);
            bfrag pb1 = *(const bfrag*)(P + (16 + l15)*136 + ks*32 + g*8);
            #pragma unroll
            for (int ct = 0; ct < 8; ++ct) {
                bfrag va = *(const bfrag*)(Vbase + (((size_t)(ct*32 + mt*4 + ks)) << 9) + lane*8);
                oacc0[ct] = __builtin_amdgcn_mfma_f32_16x16x32_bf16(va, pb0, oacc0[ct], 0, 0, 0);
                oacc1[ct] = __builtin_amdgcn_mfma_f32_16x16x32_bf16(va, pb1, oacc1[ct], 0, 0, 0);
            }
        }
        __builtin_amdgcn_s_setprio(0);
    }
    #pragma unroll
    for (int d = 1; d < 16; d <<= 1)
        #pragma unroll
        for (int r = 0; r < 4; ++r) {
            rs0[r] += __shfl_xor(rs0[r], d, 64);
            rs1[r] += __shfl_xor(rs1[r], d, 64);
        }
    if (l15 == 0) {
        #pragma unroll
        for (int r = 0; r < 4; ++r) {
            sums[g*4 + r] = rs0[r];
            sums[16 + g*4 + r] = rs1[r];
        }
    }
    float inv0 = 1.f / sums[l15];
    float inv1 = 1.f / sums[16 + l15];
    unsigned short* pb0 = part + (((size_t)n*10 + z)*128)*1024 + s0 + l15;
    #pragma unroll
    for (int ct = 0; ct < 8; ++ct)
        #pragma unroll
        for (int r = 0; r < 4; ++r) {
            pb0[(size_t)(ct*16 + g*4 + r)*1024]      = f2bf(oacc0[ct][r] * inv0);
            pb0[(size_t)(ct*16 + g*4 + r)*1024 + 16] = f2bf(oacc1[ct][r] * inv1);
        }
}

// -------- fin16T[z][s][128+c] = sum_n part[n][z][c][s]  (transposing reduce) -
__global__ __launch_bounds__(256) void reduce_part_t(
    const unsigned short* __restrict__ part, unsigned short* __restrict__ fin16T)
{
    __shared__ float tile[32][33];
    const int s0b = blockIdx.x * 32;
    const int c0b = blockIdx.y * 32;
    const int z   = blockIdx.z;
    const int tx = threadIdx.x & 31;
    const int ty = threadIdx.x >> 5;
    #pragma unroll
    for (int i = 0; i < 4; ++i) {
        int c = c0b + ty + i*8;
        float acc = 0.f;
        #pragma unroll
        for (int n = 0; n < 15; ++n)
            acc += bf2f(part[(((size_t)n*10 + z)*128 + c)*1024 + s0b + tx]);
        tile[ty + i*8][tx] = acc;
    }
    __syncthreads();
    #pragma unroll
    for (int i = 0; i < 4; ++i) {
        int s = s0b + ty + i*8;
        fin16T[((size_t)z*1024 + s)*256 + 128 + c0b + tx] = f2bf(tile[tx][ty + i*8]);
    }
}

// ---------------- G = W2' * fin + bias' : register-only bf16 MFMA GEMM ------
// grid (16 px-tiles of 64, 10 zb), block 256 (4 waves; wave -> 64 co).
__global__ __launch_bounds__(256) void g_mfma(
    const unsigned short* __restrict__ fin16T,  // [10][1024][256]
    const unsigned short* __restrict__ W2bf,    // [5][256][256]
    const float* __restrict__ biasP,            // [5][256]
    float* __restrict__ G5)                     // [10][256][1024]
{
    const int t = threadIdx.x;
    const int lane = t & 63, w = t >> 6, l15 = lane & 15, g = lane >> 4;
    const int p0 = blockIdx.x * 64;
    const int zb = blockIdx.y;
    const int lev = zb >> 1;
    const int co0 = w * 64;
    f4acc acc[4][4];
    #pragma unroll
    for (int m = 0; m < 4; ++m)
        #pragma unroll
        for (int n = 0; n < 4; ++n) acc[m][n] = (f4acc){0.f,0.f,0.f,0.f};
    const unsigned short* A = W2bf + (size_t)lev * 65536;
    const unsigned short* B = fin16T + (size_t)zb * 262144;
    for (int kc = 0; kc < 256; kc += 32) {
        bfrag a[4], b[4];
        #pragma unroll
        for (int m = 0; m < 4; ++m)
            a[m] = *((const bfrag*)(A + (size_t)(co0 + m*16 + l15)*256 + kc + g*8));
        #pragma unroll
        for (int n = 0; n < 4; ++n)
            b[n] = *((const bfrag*)(B + (size_t)(p0 + n*16 + l15)*256 + kc + g*8));
        #pragma unroll
        for (int m = 0; m < 4; ++m)
            #pragma unroll
            for (int n = 0; n < 4; ++n)
                acc[m][n] = __builtin_amdgcn_mfma_f32_16x16x32_bf16(a[m], b[n], acc[m][n], 0, 0, 0);
    }
    #pragma unroll
    for (int m = 0; m < 4; ++m)
        #pragma unroll
        for (int n = 0; n < 4; ++n) {
            int px = p0 + n*16 + l15;
            #pragma unroll
            for (int j = 0; j < 4; ++j) {
                int co = co0 + m*16 + g*4 + j;
                G5[(size_t)zb*262144 + (size_t)co*1024 + px] = acc[m][n][j] + biasP[lev*256 + co];
            }
        }
}

// -------- weight prep: W1 bf16 packed [kstep][co][32]; W2' bf16 [co][ci] ----
__global__ void prep_w(const float* __restrict__ cw, const float* __restrict__ gamma,
                       const float* __restrict__ var, unsigned short* __restrict__ W1s,
                       unsigned short* __restrict__ W2bf)
{
    int ci = blockIdx.x, co = threadIdx.x;
    W1s[(ci >> 5) * 8192 + co * 32 + (ci & 31)] = f2bf(cw[co*512 + ci]);
    for (int l = 0; l < 5; ++l) {
        float g = gamma[l*256 + ci];
        float rs = rsqrtf(var[l*256 + ci] + 1e-5f);
        W2bf[l*65536 + co*256 + ci] = f2bf(cw[co*512 + 256 + ci] * g * rs);
    }
}

__global__ void prep_bias(const float* __restrict__ cw, const float* __restrict__ cb,
                          const float* __restrict__ gamma, const float* __restrict__ beta,
                          const float* __restrict__ mean, const float* __restrict__ var,
                          float* __restrict__ biasP)
{
    int l = blockIdx.x, co = threadIdx.x;
    float acc = cb[co];
    for (int ci = 0; ci < 256; ++ci) {
        float g = gamma[l*256+ci];
        float rs = rsqrtf(var[l*256+ci] + 1e-5f);
        float k = beta[l*256+ci] - g*rs*mean[l*256+ci];
        acc += cw[co*512 + 256 + ci] * k;
    }
    biasP[l*256 + co] = acc;
}

// ---------------- out = W1*f + bilerp(G)  -- bf16 MFMA GEMM -----------------
__global__ __launch_bounds__(256) void out_mfma(
    const float* __restrict__ f, const unsigned short* __restrict__ W1s,
    const float* __restrict__ G, float* __restrict__ outp, int H, int W)
{
    __shared__ unsigned short ldsB[64 * 40];
    const int HW = H * W;
    const int p0 = blockIdx.x * 64;
    const int b  = blockIdx.y;
    const int t  = threadIdx.x;
    const int lane = t & 63;
    const int wid  = t >> 6;
    const int cw0  = wid * 64;
    const int l15  = lane & 15;
    const int g    = lane >> 4;

    f4acc acc[4][4];
    #pragma unroll
    for (int m = 0; m < 4; ++m)
        #pragma unroll
        for (int n = 0; n < 4; ++n)
            acc[m][n] = (f4acc){0.f, 0.f, 0.f, 0.f};

    const float* fb = f + (size_t)b * 256 * HW;
    const int px_st = t & 63;
    const int cg    = t >> 6;

    for (int s = 0; s < 8; ++s) {
        __syncthreads();
        {
            int p = p0 + px_st;
            bool ok = p < HW;
            const float* src = fb + (size_t)(s * 32 + cg * 8) * HW + p;
            float v[8];
            #pragma unroll
            for (int e = 0; e < 8; ++e) v[e] = ok ? src[(size_t)e * HW] : 0.f;
            unsigned u[4];
            #pragma unroll
            for (int e = 0; e < 4; ++e)
                u[e] = (unsigned)f2bf(v[2*e]) | ((unsigned)f2bf(v[2*e+1]) << 16);
            *((uint4*)&ldsB[px_st * 40 + cg * 8]) = make_uint4(u[0], u[1], u[2], u[3]);
        }
        __syncthreads();
        bfrag a[4], bb[4];
        #pragma unroll
        for (int m = 0; m < 4; ++m)
            a[m] = *((const bfrag*)(W1s + (size_t)s * 8192 + (cw0 + m*16 + l15) * 32 + g * 8));
        #pragma unroll
        for (int n = 0; n < 4; ++n)
            bb[n] = *((const bfrag*)&ldsB[(n*16 + l15) * 40 + g * 8]);
        #pragma unroll
        for (int m = 0; m < 4; ++m)
            #pragma unroll
            for (int n = 0; n < 4; ++n)
                acc[m][n] = __builtin_amdgcn_mfma_f32_16x16x32_bf16(a[m], bb[n], acc[m][n], 0, 0, 0);
    }

    const int r0 = (lane >> 4) * 4;
    #pragma unroll
    for (int n = 0; n < 4; ++n) {
        int px = p0 + n*16 + l15;
        if (px >= HW) continue;
        int yy = px / W;
        int xx = px - yy * W;
        float ty = (float)(yy * 31) / (float)(H - 1);
        float tx = (float)(xx * 31) / (float)(W - 1);
        int y0 = (int)ty; float wy = ty - y0;
        int x0 = (int)tx; float wx = tx - x0;
        int y1 = min(y0 + 1, 31), x1 = min(x0 + 1, 31);
        float w00 = (1.f-wy)*(1.f-wx), w01 = (1.f-wy)*wx;
        float w10 = wy*(1.f-wx),       w11 = wy*wx;
        int i00 = y0*32+x0, i01 = y0*32+x1, i10 = y1*32+x0, i11 = y1*32+x1;
        #pragma unroll
        for (int m = 0; m < 4; ++m) {
            #pragma unroll
            for (int j = 0; j < 4; ++j) {
                int co = cw0 + m*16 + r0 + j;
                const float* gb = G + ((size_t)b*256 + co) * 1024;
                float gv = gb[i00]*w00 + gb[i01]*w01 + gb[i10]*w10 + gb[i11]*w11;
                outp[((size_t)b*256 + co) * HW + px] = acc[m][n][j] + gv;
            }
        }
    }
}

extern "C" void kernel_launch(void* const* d_in, const int* in_sizes, int n_in,
                              void* d_out, int out_size, void* d_ws, size_t ws_size,
                              hipStream_t stream)
{
    const float* f[5]; for (int i = 0; i < 5; ++i) f[i] = (const float*)d_in[i];
    const float* att   = (const float*)d_in[5];
    const float* ktw   = (const float*)d_in[6];
    const float* ktb   = (const float*)d_in[7];
    const float* vtw   = (const float*)d_in[8];
    const float* vtb   = (const float*)d_in[9];
    const float* kqw   = (const float*)d_in[10];
    const float* kqbb  = (const float*)d_in[11];
    const float* vqw   = (const float*)d_in[12];
    const float* vqb   = (const float*)d_in[13];
    const float* gamma = (const float*)d_in[14];
    const float* beta  = (const float*)d_in[15];
    const float* mean  = (const float*)d_in[16];
    const float* var   = (const float*)d_in[17];
    const float* cw    = (const float*)d_in[18];
    const float* cb    = (const float*)d_in[19];
    float* outp = (float*)d_out;

    unsigned short* ktT16 = (unsigned short*)d_ws;      // 491520 u16
    unsigned short* kqT16 = ktT16 + 491520;             // 327680
    unsigned short* vt16  = kqT16 + 327680;             // 1966080
    unsigned short* wpkt  = vt16 + 1966080;             // 73728
    unsigned short* wpvt  = wpkt + 73728;               // 294912
    unsigned short* wpkq  = wpvt + 294912;              // 368640
    unsigned short* wpvq  = wpkq + 368640;              // 1474560
    unsigned short* W1s   = wpvq + 1474560;             // 65536
    unsigned short* W2bf  = W1s + 65536;                // 327680
    unsigned short* fin16T= W2bf + 327680;              // 2621440
    unsigned short* partb = fin16T + 2621440;           // 19660800
    float* biasP = (float*)(partb + 19660800);          // 1280 f
    float* fr5   = biasP + 1280;                        // 2621440 f
    float* G5    = fr5 + 2621440;                       // 2621440 f

    prep_w<<<256, 256, 0, stream>>>(cw, gamma, var, W1s, W2bf);
    prep_bias<<<5, 256, 0, stream>>>(cw, cb, gamma, beta, mean, var, biasP);
    pack_w<<<dim3(288, 1),  256, 0, stream>>>(ktw, wpkt, 32);
    pack_w<<<dim3(1152, 1), 256, 0, stream>>>(vtw, wpvt, 128);
    pack_w<<<dim3(288, 5),  256, 0, stream>>>(kqw, wpkq, 32);
    pack_w<<<dim3(1152, 5), 256, 0, stream>>>(vqw, wpvq, 128);

    convgemm<32, 1><<<dim3(8, 15), 256, 0, stream>>>(att, wpkt, 0, ktb, 0, ktT16, 1.f);
    convgemm<128, 2><<<dim3(8, 15), 256, 0, stream>>>(att, wpvt, 0, vtb, 0, vt16, 1.f);

    const int Hs[5] = {200,100,50,25,13};
    const int Ws[5] = {336,168,84,42,21};
    for (int l = 0; l < 5; ++l)
        resize32<<<2048, 256, 0, stream>>>(f[l], fr5 + (size_t)l*524288, Hs[l], Ws[l]);

    convgemm<32, 1><<<dim3(8, 10), 256, 0, stream>>>(fr5, wpkq, 73728, kqbb, 32, kqT16, 1.f);
    convgemm<128, 3><<<dim3(8, 10), 256, 0, stream>>>(fr5, wpvq, 294912, vqb, 128, fin16T, 15.f);

    attn_mfma<<<dim3(32, 15, 10), 64, 0, stream>>>(kqT16, ktT16, vt16, partb);
    reduce_part_t<<<dim3(32, 4, 10), 256, 0, stream>>>(partb, fin16T);
    g_mfma<<<dim3(16, 10), 256, 0, stream>>>(fin16T, W2bf, biasP, G5);

    size_t ooff = 0;
    for (int l = 0; l < 5; ++l) {
        int H = Hs[l], W = Ws[l], HW = H*W;
        out_mfma<<<dim3((HW+63)/64, 2), 256, 0, stream>>>(f[l], W1s, G5 + (size_t)l*524288, outp + ooff, H, W);
        ooff += (size_t)2*256*HW;
    }
}